// Round 5
// baseline (2489.895 us; speedup 1.0000x reference)
//
#include <hip/hip_runtime.h>
#include <hip/hip_bf16.h>
#include <math.h>

// ---------------------------------------------------------------------------
// BashTransformer forward on MI355X. Round 5: shfl-free register-resident
// delta scan (full S row per lane, descaled state, ping-pong prefetch),
// silu fused into gate-up GEMM epilogue, MFMA flash attn, bf16 MFMA GEMMs.
// ---------------------------------------------------------------------------

#define LSEQ 1024
#define BATCH 4
#define HIDDEN 512
#define NHEAD 8
#define HDIM 64
#define SHEAD 8
#define SDHD 32
#define SDIMM 256
#define FFND 1536
#define VOCN 63
#define ATTS 72   // attn LDS row stride (elems): 144B = 16B-aligned, 2-way banks

typedef __bf16 bf16;
typedef __attribute__((ext_vector_type(8))) __bf16 bf16x8;
typedef __attribute__((ext_vector_type(4))) float floatx4;

union BF4 { bf16 h[4]; short4 p; };

__device__ __forceinline__ void gload16(const void* g, const void* l) {
    __builtin_amdgcn_global_load_lds(
        (__attribute__((address_space(1))) unsigned int*)(uintptr_t)g,
        (__attribute__((address_space(3))) unsigned int*)(unsigned int)(uintptr_t)l,
        16, 0, 0);
}

// ------------------------------- rope tables -------------------------------
__global__ void rope_tables_k(float* __restrict__ cosT, float* __restrict__ sinT) {
    int idx = blockIdx.x * 256 + threadIdx.x;   // 32768 = 1024*32
    int l = idx >> 5, d = idx & 31;
    double ang = (double)l * pow(500000.0, -(double)(2 * d) / 64.0);
    cosT[idx] = (float)cos(ang);
    sinT[idx] = (float)sin(ang);
}

// ------------------------------- embedding ---------------------------------
__global__ void embed_k(const int* __restrict__ ids, const float* __restrict__ emb,
                        float* __restrict__ h) {
    int tok = blockIdx.x;
    int id = ids[tok];
    ((float4*)(h + (size_t)tok * HIDDEN))[threadIdx.x] =
        ((const float4*)(emb + (size_t)id * HIDDEN))[threadIdx.x];
}

// ------------------------------- casts -------------------------------------
__global__ void cast_plain(const float* __restrict__ s, bf16* __restrict__ d, int n4) {
    int i = blockIdx.x * 256 + threadIdx.x;
    if (i >= n4) return;
    float4 v = ((const float4*)s)[i];
    BF4 u;
    u.h[0] = (bf16)v.x; u.h[1] = (bf16)v.y; u.h[2] = (bf16)v.z; u.h[3] = (bf16)v.w;
    ((short4*)d)[i] = u.p;
}

// six 256x512 f32 matrices -> one fused 1536x512 bf16 (order s0..s5)
__global__ void cast6(const float* s0, const float* s1, const float* s2,
                      const float* s3, const float* s4, const float* s5,
                      bf16* __restrict__ d) {
    int i = blockIdx.x * 256 + threadIdx.x;      // 196608 short4s
    if (i >= 196608) return;
    int which = i >> 15, loc = i & 32767;
    const float* s = which == 0 ? s0 : which == 1 ? s1 : which == 2 ? s2
                    : which == 3 ? s3 : which == 4 ? s4 : s5;
    float4 v = ((const float4*)s)[loc];
    BF4 u;
    u.h[0] = (bf16)v.x; u.h[1] = (bf16)v.y; u.h[2] = (bf16)v.z; u.h[3] = (bf16)v.w;
    ((short4*)d)[i] = u.p;
}

// gather (layers,R,K) f32 -> fused bf16 rows [i*dstStride + dstOff + r*rowMul]
__global__ void cast_fuse(const float* __restrict__ s, bf16* __restrict__ d,
                          int R, int K4, int dstStride, int dstOff, int rowMul,
                          int total4) {
    int idx = blockIdx.x * 256 + threadIdx.x;
    if (idx >= total4) return;
    int perLayer = R * K4;
    int i = idx / perLayer;
    int rem = idx - i * perLayer;
    int r = rem / K4, c4 = rem - r * K4;
    float4 v = ((const float4*)s)[idx];
    BF4 u;
    u.h[0] = (bf16)v.x; u.h[1] = (bf16)v.y; u.h[2] = (bf16)v.z; u.h[3] = (bf16)v.w;
    ((short4*)d)[((size_t)i * dstStride + dstOff + r * rowMul) * K4 + c4] = u.p;
}

__global__ void cast_embed_pad(const float* __restrict__ s, bf16* __restrict__ d) {
    int i = blockIdx.x * 256 + threadIdx.x;   // 128*128 = 16384 short4s
    int row = i >> 7, c4 = i & 127;
    BF4 u;
    if (row < VOCN) {
        float4 v = ((const float4*)s)[row * 128 + c4];
        u.h[0] = (bf16)v.x; u.h[1] = (bf16)v.y; u.h[2] = (bf16)v.z; u.h[3] = (bf16)v.w;
    } else {
        u.h[0] = (bf16)0.f; u.h[1] = (bf16)0.f; u.h[2] = (bf16)0.f; u.h[3] = (bf16)0.f;
    }
    ((short4*)d)[i] = u.p;
}

// ------------------------------- rmsnorm -> bf16 ---------------------------
__global__ void rmsnorm512(const float* __restrict__ in, const float* __restrict__ w,
                           bf16* __restrict__ out) {
    int row = blockIdx.x, t = threadIdx.x;     // 128 threads
    float4 x = ((const float4*)(in + (size_t)row * 512))[t];
    float s = x.x * x.x + x.y * x.y + x.z * x.z + x.w * x.w;
    for (int m = 1; m < 64; m <<= 1) s += __shfl_xor(s, m);
    __shared__ float red[2];
    if ((t & 63) == 0) red[t >> 6] = s;
    __syncthreads();
    float tot = red[0] + red[1];
    float r = rsqrtf(tot * (1.f / 512.f) + 1e-6f);
    float4 wv = ((const float4*)w)[t];
    BF4 u;
    u.h[0] = (bf16)(x.x * r * wv.x); u.h[1] = (bf16)(x.y * r * wv.y);
    u.h[2] = (bf16)(x.z * r * wv.z); u.h[3] = (bf16)(x.w * r * wv.w);
    ((short4*)(out + (size_t)row * 512))[t] = u.p;
}

// ------------------------------- bf16 MFMA GEMM ----------------------------
// C = A(bf16, MxK rm) @ B(bf16, NxK rm)^T. 128x128 tile, Kstep 32, 4 waves.
// MODE 0: C(f32)=v  MODE 1: C(f32)+=v
// MODE 4: gate/up interleaved cols (even=gate,odd=up); Cb[row*Nreal + col/2]
//         = bf16(silu(gate)*up), Nreal = N/2.
template <int MODE>
__global__ __launch_bounds__(256) void gemm_bf16(const bf16* __restrict__ A,
                                                 const bf16* __restrict__ B,
                                                 float* __restrict__ C,
                                                 bf16* __restrict__ Cb,
                                                 int M, int N, int K, int Nreal) {
    __shared__ bf16 As[128 * 32];
    __shared__ bf16 Bs[128 * 32];
    const int tid = threadIdx.x;
    const int wave = tid >> 6, lane = tid & 63;
    const int row0 = blockIdx.y * 128, col0 = blockIdx.x * 128;
    floatx4 acc[4][4];
#pragma unroll
    for (int i = 0; i < 4; ++i)
#pragma unroll
        for (int j = 0; j < 4; ++j) acc[i][j] = (floatx4){0.f, 0.f, 0.f, 0.f};
    const int m0 = (wave & 1) * 64, n0 = (wave >> 1) * 64;
    const int sr = tid >> 2;
    const int ske = (tid & 3) * 8;
    const size_t arow1 = (size_t)(row0 + sr) * K + ske;
    const size_t arow2 = (size_t)(row0 + 64 + sr) * K + ske;
    const size_t brow1 = (size_t)(col0 + sr) * K + ske;
    const size_t brow2 = (size_t)(col0 + 64 + sr) * K + ske;
    char* AsB = (char*)As;
    char* BsB = (char*)Bs;
    const int lds0 = wave * 1024, lds1 = 4096 + wave * 1024;

    for (int k0 = 0; k0 < K; k0 += 32) {
        gload16(A + arow1 + k0, AsB + lds0);
        gload16(A + arow2 + k0, AsB + lds1);
        gload16(B + brow1 + k0, BsB + lds0);
        gload16(B + brow2 + k0, BsB + lds1);
        __syncthreads();
        bf16x8 af[4], bfr[4];
#pragma unroll
        for (int mi = 0; mi < 4; ++mi)
            af[mi] = *(const bf16x8*)(AsB + ((m0 + mi * 16 + (lane & 15)) * 32 + (lane >> 4) * 8) * 2);
#pragma unroll
        for (int ni = 0; ni < 4; ++ni)
            bfr[ni] = *(const bf16x8*)(BsB + ((n0 + ni * 16 + (lane & 15)) * 32 + (lane >> 4) * 8) * 2);
#pragma unroll
        for (int mi = 0; mi < 4; ++mi)
#pragma unroll
            for (int ni = 0; ni < 4; ++ni)
                acc[mi][ni] = __builtin_amdgcn_mfma_f32_16x16x32_bf16(af[mi], bfr[ni], acc[mi][ni], 0, 0, 0);
        __syncthreads();
    }
    const int cr = (lane >> 4) * 4;
    const int cc = lane & 15;
#pragma unroll
    for (int mi = 0; mi < 4; ++mi) {
#pragma unroll
        for (int ni = 0; ni < 4; ++ni) {
#pragma unroll
            for (int r = 0; r < 4; ++r) {
                int row = row0 + m0 + mi * 16 + cr + r;
                int col = col0 + n0 + ni * 16 + cc;
                float v = acc[mi][ni][r];
                if (MODE == 4) {
                    float o = __shfl_xor(v, 1);
                    if (!(lane & 1)) {
                        float sg = v / (1.f + __expf(-v));
                        Cb[(size_t)row * Nreal + (col >> 1)] = (bf16)(sg * o);
                    }
                } else if (col < Nreal) {
                    size_t off = (size_t)row * Nreal + col;
                    if (MODE == 0) C[off] = v;
                    else if (MODE == 1) C[off] += v;
                }
            }
        }
    }
}

// ----------------- QKV prep: RoPE + bf16 cast + V transpose ----------------
__global__ void qkv_prep(const float* __restrict__ P, const float* __restrict__ cosT,
                         const float* __restrict__ sinT, bf16* __restrict__ Qb,
                         bf16* __restrict__ Kb, bf16* __restrict__ Vtb) {
    int tok = blockIdx.x;                       // 4096
    int b = tok >> 10, l = tok & 1023;
    int hh = threadIdx.x >> 5, d = threadIdx.x & 31;
    const float* q = P + (size_t)tok * 1536 + hh * 64;
    const float* k = q + 512;
    const float* v = q + 1024;
    float c = cosT[l * 32 + d], s = sinT[l * 32 + d];
    size_t base = ((size_t)(b * 8 + hh) * 1024 + l) * 64;
    float q1 = q[d], q2 = q[d + 32];
    Qb[base + d] = (bf16)(q1 * c - q2 * s);
    Qb[base + d + 32] = (bf16)(q2 * c + q1 * s);
    float k1 = k[d], k2 = k[d + 32];
    Kb[base + d] = (bf16)(k1 * c - k2 * s);
    Kb[base + d + 32] = (bf16)(k2 * c + k1 * s);
    size_t vb = (size_t)(b * 8 + hh) * 64 * 1024 + l;
    Vtb[vb + (size_t)d * 1024] = (bf16)v[d];
    Vtb[vb + (size_t)(d + 32) * 1024] = (bf16)v[d + 32];
}

// ------------------------- MFMA flash attention ----------------------------
__global__ __launch_bounds__(256) void attn_mfma(const bf16* __restrict__ Qb,
                                                 const bf16* __restrict__ Kb,
                                                 const bf16* __restrict__ Vtb,
                                                 bf16* __restrict__ O) {
    int qt = blockIdx.x, hh = blockIdx.y, b = blockIdx.z;
    int bh = b * 8 + hh;
    int q0 = qt * 64;
    const bf16* Qg = Qb + ((size_t)bh * 1024 + q0) * 64;
    const bf16* Kg = Kb + (size_t)bh * 1024 * 64;
    const bf16* Vg = Vtb + (size_t)bh * 64 * 1024;   // [64 d][1024 l]
    __shared__ bf16 Qs[64 * ATTS];
    __shared__ bf16 Ks[64 * ATTS];
    __shared__ bf16 Vs[64 * ATTS];
    __shared__ bf16 Ps[64 * ATTS];
    int tid = threadIdx.x, wave = tid >> 6, lane = tid & 63;
    int lr = lane & 15, quad = lane >> 4;

#pragma unroll
    for (int it = 0; it < 2; ++it) {
        int cidx = tid + it * 256;
        int row = cidx >> 3, ch = cidx & 7;
        *(bf16x8*)(Qs + row * ATTS + ch * 8) = *(const bf16x8*)(Qg + row * 64 + ch * 8);
    }
    float mrow[4], lrow[4];
    floatx4 Oacc[4];
#pragma unroll
    for (int r = 0; r < 4; ++r) { mrow[r] = -1e30f; lrow[r] = 0.f; }
#pragma unroll
    for (int d0 = 0; d0 < 4; ++d0) Oacc[d0] = (floatx4){0.f, 0.f, 0.f, 0.f};

    int ntiles = qt + 1;
    for (int t = 0; t < ntiles; ++t) {
        int kv0 = t * 64;
        __syncthreads();
#pragma unroll
        for (int it = 0; it < 2; ++it) {
            int cidx = tid + it * 256;
            int row = cidx >> 3, ch = cidx & 7;
            *(bf16x8*)(Ks + row * ATTS + ch * 8) =
                *(const bf16x8*)(Kg + (size_t)(kv0 + row) * 64 + ch * 8);
            *(bf16x8*)(Vs + row * ATTS + ch * 8) =
                *(const bf16x8*)(Vg + (size_t)row * 1024 + kv0 + ch * 8);
        }
        __syncthreads();
        bf16x8 aq[2];
#pragma unroll
        for (int kc = 0; kc < 2; ++kc)
            aq[kc] = *(const bf16x8*)(Qs + (wave * 16 + lr) * ATTS + kc * 32 + quad * 8);
        floatx4 sacc[4];
#pragma unroll
        for (int n0 = 0; n0 < 4; ++n0) {
            bf16x8 bk0 = *(const bf16x8*)(Ks + (n0 * 16 + lr) * ATTS + quad * 8);
            bf16x8 bk1 = *(const bf16x8*)(Ks + (n0 * 16 + lr) * ATTS + 32 + quad * 8);
            floatx4 z = (floatx4){0.f, 0.f, 0.f, 0.f};
            z = __builtin_amdgcn_mfma_f32_16x16x32_bf16(aq[0], bk0, z, 0, 0, 0);
            sacc[n0] = __builtin_amdgcn_mfma_f32_16x16x32_bf16(aq[1], bk1, z, 0, 0, 0);
        }
        float sv[4][4];
#pragma unroll
        for (int n0 = 0; n0 < 4; ++n0)
#pragma unroll
            for (int r = 0; r < 4; ++r) sv[n0][r] = sacc[n0][r] * 0.125f;
        if (t == ntiles - 1) {
#pragma unroll
            for (int n0 = 0; n0 < 4; ++n0)
#pragma unroll
                for (int r = 0; r < 4; ++r)
                    if (n0 * 16 + lr > wave * 16 + quad * 4 + r) sv[n0][r] = -1e30f;
        }
        float al[4];
#pragma unroll
        for (int r = 0; r < 4; ++r) {
            float tm = fmaxf(fmaxf(sv[0][r], sv[1][r]), fmaxf(sv[2][r], sv[3][r]));
            tm = fmaxf(tm, __shfl_xor(tm, 1));
            tm = fmaxf(tm, __shfl_xor(tm, 2));
            tm = fmaxf(tm, __shfl_xor(tm, 4));
            tm = fmaxf(tm, __shfl_xor(tm, 8));
            float mn = fmaxf(mrow[r], tm);
            al[r] = __expf(mrow[r] - mn);
            mrow[r] = mn;
        }
        float rs[4];
#pragma unroll
        for (int r = 0; r < 4; ++r) rs[r] = 0.f;
#pragma unroll
        for (int n0 = 0; n0 < 4; ++n0)
#pragma unroll
            for (int r = 0; r < 4; ++r) {
                float p = __expf(sv[n0][r] - mrow[r]);
                sv[n0][r] = p;
                rs[r] += p;
            }
#pragma unroll
        for (int r = 0; r < 4; ++r) {
            float t2 = rs[r];
            t2 += __shfl_xor(t2, 1);
            t2 += __shfl_xor(t2, 2);
            t2 += __shfl_xor(t2, 4);
            t2 += __shfl_xor(t2, 8);
            lrow[r] = lrow[r] * al[r] + t2;
        }
#pragma unroll
        for (int d0 = 0; d0 < 4; ++d0)
#pragma unroll
            for (int r = 0; r < 4; ++r) Oacc[d0][r] *= al[r];
#pragma unroll
        for (int n0 = 0; n0 < 4; ++n0)
#pragma unroll
            for (int r = 0; r < 4; ++r)
                Ps[(wave * 16 + quad * 4 + r) * ATTS + n0 * 16 + lr] = (bf16)sv[n0][r];
        bf16x8 ap[2];
#pragma unroll
        for (int kc = 0; kc < 2; ++kc)
            ap[kc] = *(const bf16x8*)(Ps + (wave * 16 + lr) * ATTS + kc * 32 + quad * 8);
#pragma unroll
        for (int d0 = 0; d0 < 4; ++d0) {
            bf16x8 bv0 = *(const bf16x8*)(Vs + (d0 * 16 + lr) * ATTS + quad * 8);
            bf16x8 bv1 = *(const bf16x8*)(Vs + (d0 * 16 + lr) * ATTS + 32 + quad * 8);
            Oacc[d0] = __builtin_amdgcn_mfma_f32_16x16x32_bf16(ap[0], bv0, Oacc[d0], 0, 0, 0);
            Oacc[d0] = __builtin_amdgcn_mfma_f32_16x16x32_bf16(ap[1], bv1, Oacc[d0], 0, 0, 0);
        }
    }
    float inv[4];
#pragma unroll
    for (int r = 0; r < 4; ++r) inv[r] = 1.f / lrow[r];
#pragma unroll
    for (int d0 = 0; d0 < 4; ++d0)
#pragma unroll
        for (int r = 0; r < 4; ++r) {
            int row = b * 1024 + q0 + wave * 16 + quad * 4 + r;
            int col = hh * 64 + d0 * 16 + lr;
            O[(size_t)row * 512 + col] = (bf16)(Oacc[d0][r] * inv[r]);
        }
}

// ------------------------------- delta scan --------------------------------
// 16 blocks x 1 wave; 2 heads per wave (p = lane>>5), lane owns full S row
// i = lane&31 in 32 VGPRs. No cross-lane ops. State kept descaled: S_real =
// D * S with per-row running decay D; __any-guarded rescale avoids underflow.
__global__ __launch_bounds__(64, 1) void delta_scan(
    const float* __restrict__ P, const float* __restrict__ S_in,
    const float* __restrict__ bbias, const float* __restrict__ abias,
    float* __restrict__ S_out, float* __restrict__ ctx) {
    int lane = threadIdx.x;
    int p = lane >> 5, i = lane & 31;
    int bh = blockIdx.x * 2 + p;
    int b = bh >> 3, hh = bh & 7;
    __shared__ float ks[2][66][36], qs[2][66][36], vs[2][66][36],
                     bs[2][66][36], as_[2][66][36];
    float4 S[8];
    {
        const float4* Sp = (const float4*)(S_in + ((size_t)bh * 32 + i) * 32);
#pragma unroll
        for (int m = 0; m < 8; ++m) S[m] = Sp[m];
    }
    int c4 = i & 7, r0 = i >> 3;
    float4 bB = *(const float4*)(bbias + hh * 32 + c4 * 4);
    float4 bA = *(const float4*)(abias + hh * 32 + c4 * 4);
    float D = 1.f, Dinv = 1.f;

    float4 ka[8], qa[8], kb[8], qb[8];
    float aa, ba, va, a2, b2, v2;

    auto loadt = [&](int tt, float4* kk, float4* qq, float& ax, float& bx, float& vx) {
#pragma unroll
        for (int j4 = 0; j4 < 8; ++j4) {
            kk[j4] = *(const float4*)&ks[p][tt][j4 * 4];
            qq[j4] = *(const float4*)&qs[p][tt][j4 * 4];
        }
        ax = as_[p][tt][i]; bx = bs[p][tt][i]; vx = vs[p][tt][i];
    };
    auto stepf = [&](const float4* kk, const float4* qq, float ax, float bx, float vx,
                     int gtok) {
        float d0 = 0.f, d1 = 0.f, d2 = 0.f, d3 = 0.f;
#pragma unroll
        for (int m = 0; m < 8; m += 4) {
            d0 = fmaf(S[m].w, kk[m].w, fmaf(S[m].z, kk[m].z,
                 fmaf(S[m].y, kk[m].y, fmaf(S[m].x, kk[m].x, d0))));
            d1 = fmaf(S[m+1].w, kk[m+1].w, fmaf(S[m+1].z, kk[m+1].z,
                 fmaf(S[m+1].y, kk[m+1].y, fmaf(S[m+1].x, kk[m+1].x, d1))));
            d2 = fmaf(S[m+2].w, kk[m+2].w, fmaf(S[m+2].z, kk[m+2].z,
                 fmaf(S[m+2].y, kk[m+2].y, fmaf(S[m+2].x, kk[m+2].x, d2))));
            d3 = fmaf(S[m+3].w, kk[m+3].w, fmaf(S[m+3].z, kk[m+3].z,
                 fmaf(S[m+3].y, kk[m+3].y, fmaf(S[m+3].x, kk[m+3].x, d3))));
        }
        float dot = (d0 + d1) + (d2 + d3);
        float u = bx * (vx - ax * (D * dot));
        D *= ax;
        Dinv *= __builtin_amdgcn_rcpf(ax);
        if (__any(D < 1e-10f)) {
#pragma unroll
            for (int m = 0; m < 8; ++m) {
                S[m].x *= D; S[m].y *= D; S[m].z *= D; S[m].w *= D;
            }
            D = 1.f; Dinv = 1.f;
        }
        float ud = u * Dinv;
#pragma unroll
        for (int m = 0; m < 8; ++m) {
            S[m].x = fmaf(ud, kk[m].x, S[m].x);
            S[m].y = fmaf(ud, kk[m].y, S[m].y);
            S[m].z = fmaf(ud, kk[m].z, S[m].z);
            S[m].w = fmaf(ud, kk[m].w, S[m].w);
        }
        float e0 = 0.f, e1 = 0.f, e2 = 0.f, e3 = 0.f;
#pragma unroll
        for (int m = 0; m < 8; m += 4) {
            e0 = fmaf(S[m].w, qq[m].w, fmaf(S[m].z, qq[m].z,
                 fmaf(S[m].y, qq[m].y, fmaf(S[m].x, qq[m].x, e0))));
            e1 = fmaf(S[m+1].w, qq[m+1].w, fmaf(S[m+1].z, qq[m+1].z,
                 fmaf(S[m+1].y, qq[m+1].y, fmaf(S[m+1].x, qq[m+1].x, e1))));
            e2 = fmaf(S[m+2].w, qq[m+2].w, fmaf(S[m+2].z, qq[m+2].z,
                 fmaf(S[m+2].y, qq[m+2].y, fmaf(S[m+2].x, qq[m+2].x, e2))));
            e3 = fmaf(S[m+3].w, qq[m+3].w, fmaf(S[m+3].z, qq[m+3].z,
                 fmaf(S[m+3].y, qq[m+3].y, fmaf(S[m+3].x, qq[m+3].x, e3))));
        }
        float rdd = (e0 + e1) + (e2 + e3);
        ctx[(size_t)gtok * 256 + hh * 32 + i] = D * rdd;
    };

    for (int c0 = 0; c0 < LSEQ; c0 += 64) {
        __syncthreads();
        const float* Pb = P + ((size_t)(b * 1024 + c0) * 1536) + hh * 32 + c4 * 4;
#pragma unroll 4
        for (int it = 0; it < 16; ++it) {
            int row = r0 + it * 4;
            const float* pg = Pb + (size_t)row * 1536;
            float4 kv = *(const float4*)(pg);
            float4 vv = *(const float4*)(pg + 256);
            float4 qv = *(const float4*)(pg + 512);
            float4 bv = *(const float4*)(pg + 768);
            float4 av = *(const float4*)(pg + 1024);
            *(float4*)&ks[p][row][c4 * 4] = kv;
            *(float4*)&vs[p][row][c4 * 4] = vv;
            *(float4*)&qs[p][row][c4 * 4] = qv;
            float4 bo, ao;
            bo.x = 1.f / (1.f + __expf(-(bv.x + bB.x)));
            bo.y = 1.f / (1.f + __expf(-(bv.y + bB.y)));
            bo.z = 1.f / (1.f + __expf(-(bv.z + bB.z)));
            bo.w = 1.f / (1.f + __expf(-(bv.w + bB.w)));
            ao.x = 1.f / (1.f + __expf(-(av.x + bA.x)));
            ao.y = 1.f / (1.f + __expf(-(av.y + bA.y)));
            ao.z = 1.f / (1.f + __expf(-(av.z + bA.z)));
            ao.w = 1.f / (1.f + __expf(-(av.w + bA.w)));
            *(float4*)&bs[p][row][c4 * 4] = bo;
            *(float4*)&as_[p][row][c4 * 4] = ao;
        }
        __syncthreads();
        // normalize k rows (2 per lane)
#pragma unroll
        for (int rr = 0; rr < 2; ++rr) {
            int t = i * 2 + rr;
            float s = 0.f;
#pragma unroll
            for (int j4 = 0; j4 < 8; ++j4) {
                float4 kv = *(const float4*)&ks[p][t][j4 * 4];
                s += kv.x * kv.x + kv.y * kv.y + kv.z * kv.z + kv.w * kv.w;
            }
            float rn = 1.f / fmaxf(sqrtf(s), 1e-12f);
#pragma unroll
            for (int j4 = 0; j4 < 8; ++j4) {
                float4 kv = *(const float4*)&ks[p][t][j4 * 4];
                kv.x *= rn; kv.y *= rn; kv.z *= rn; kv.w *= rn;
                *(float4*)&ks[p][t][j4 * 4] = kv;
            }
        }
        __syncthreads();
        int gbase = b * 1024 + c0;
        loadt(0, ka, qa, aa, ba, va);
        for (int t = 0; t < 64; t += 2) {
            loadt(t + 1, kb, qb, a2, b2, v2);
            stepf(ka, qa, aa, ba, va, gbase + t);
            loadt(t + 2, ka, qa, aa, ba, va);   // row 64/65 padded: garbage ok
            stepf(kb, qb, a2, b2, v2, gbase + t + 1);
        }
    }
#pragma unroll
    for (int m = 0; m < 8; ++m) {
        S[m].x *= D; S[m].y *= D; S[m].z *= D; S[m].w *= D;
    }
    float4* So = (float4*)(S_out + ((size_t)bh * 32 + i) * 32);
#pragma unroll
    for (int m = 0; m < 8; ++m) So[m] = S[m];
}

// ------------- ctxbf = bf16(rmsnorm(ctx,nw)*silu(gate)), gate in P@1280 ----
__global__ void ctx_post(const float* __restrict__ ctx, const float* __restrict__ P,
                         const float* __restrict__ nw, bf16* __restrict__ out) {
    int row = blockIdx.x, t = threadIdx.x;  // 64 threads
    float4 x = ((const float4*)(ctx + (size_t)row * SDIMM))[t];
    float s = x.x * x.x + x.y * x.y + x.z * x.z + x.w * x.w;
    for (int m = 1; m < 64; m <<= 1) s += __shfl_xor(s, m);
    float r = rsqrtf(s * (1.f / 256.f) + 1e-6f);
    float4 n = ((const float4*)nw)[t];
    float4 g = ((const float4*)(P + (size_t)row * 1536 + 1280))[t];
    BF4 u;
    u.h[0] = (bf16)(x.x * r * n.x * (g.x / (1.f + __expf(-g.x))));
    u.h[1] = (bf16)(x.y * r * n.y * (g.y / (1.f + __expf(-g.y))));
    u.h[2] = (bf16)(x.z * r * n.z * (g.z / (1.f + __expf(-g.z))));
    u.h[3] = (bf16)(x.w * r * n.w * (g.w / (1.f + __expf(-g.w))));
    ((short4*)(out + (size_t)row * SDIMM))[t] = u.p;
}

// ---------------------------------------------------------------------------
extern "C" void kernel_launch(void* const* d_in, const int* in_sizes, int n_in,
                              void* d_out, int out_size, void* d_ws, size_t ws_size,
                              hipStream_t stream) {
    (void)in_sizes; (void)n_in; (void)out_size; (void)ws_size;
    const int* ids = (const int*)d_in[0];
    const float* state = (const float*)d_in[1];
    const float* embedw = (const float*)d_in[2];
    auto F = [&](int i) { return (const float*)d_in[i]; };

    char* wsb = (char*)d_ws;
    const size_t MB = 1048576;
    float* H    = (float*)(wsb);                 // 0-8 MB
    bf16*  XNbf = (bf16*)(wsb + 8 * MB);         // 8-12 (alias ctxf in delta)
    float* ctxf = (float*)(wsb + 8 * MB);
    bf16*  Hbf  = (bf16*)(wsb + 12 * MB);        // 12-16 (alias ctxb)
    bf16*  ctxb = (bf16*)(wsb + 12 * MB);
    float* P    = (float*)(wsb + 16 * MB);       // 16-40 (QKV f32 / delta f32)
    bf16*  Obf  = (bf16*)(wsb + 40 * MB);        // 40-44 attn out
    bf16*  Qbuf = (bf16*)(wsb + 44 * MB);        // 44-48
    bf16*  Kbuf = (bf16*)(wsb + 48 * MB);        // 48-52
    bf16*  Vtb  = (bf16*)(wsb + 52 * MB);        // 52-56
    bf16*  A1b  = (bf16*)(wsb + 44 * MB);        // alias Q/K/Vt (dead after attn)
    float* cosT = (float*)(wsb + 58 * MB);
    float* sinT = cosT + 32768;
    float* Sbuf = sinT + 32768;
    char*  wbase = wsb + 59 * MB;
    bf16* wqkv  = (bf16*)(wbase);                        // 6x1536x512
    bf16* wob   = (bf16*)(wbase + 9437184);              // 6x512x512
    bf16* wgu   = (bf16*)(wbase + 12582912);             // 6x3072x512 interleaved
    bf16* wdnb  = (bf16*)(wbase + 31457280);             // 6x512x1536
    bf16* wdR   = (bf16*)(wbase + 40894464);             // 1536x512
    bf16* woutR = (bf16*)(wbase + 42467328);             // 512x256
    bf16* wdW   = (bf16*)(wbase + 42729472);             // 1536x512
    bf16* woutW = (bf16*)(wbase + 44302336);             // 512x256
    bf16* embp  = (bf16*)(wbase + 44564480);             // 128x512 padded

    float* out = (float*)d_out;
    float* logits = out;
    float* Sout = out + 4096 * VOCN;

    auto G = [&](int mode, const bf16* A, const bf16* B, float* C, bf16* Cb,
                 int M, int N, int K, int Nreal) {
        dim3 grid(N / 128, M / 128);
        if (mode == 0) gemm_bf16<0><<<grid, 256, 0, stream>>>(A, B, C, Cb, M, N, K, Nreal);
        else if (mode == 1) gemm_bf16<1><<<grid, 256, 0, stream>>>(A, B, C, Cb, M, N, K, Nreal);
        else gemm_bf16<4><<<grid, 256, 0, stream>>>(A, B, C, Cb, M, N, K, Nreal);
    };
    auto CP = [&](const float* s, bf16* d, int n4) {
        cast_plain<<<(n4 + 255) / 256, 256, 0, stream>>>(s, d, n4);
    };

    // ---- weight casts ----
    cast_fuse<<<1536, 256, 0, stream>>>(F(24), wqkv, 512, 128, 1536, 0, 1, 393216);
    cast_fuse<<<1536, 256, 0, stream>>>(F(25), wqkv, 512, 128, 1536, 512, 1, 393216);
    cast_fuse<<<1536, 256, 0, stream>>>(F(26), wqkv, 512, 128, 1536, 1024, 1, 393216);
    CP(F(27), wob, 393216);
    cast_fuse<<<4608, 256, 0, stream>>>(F(29), wgu, 1536, 128, 3072, 0, 2, 1179648);
    cast_fuse<<<4608, 256, 0, stream>>>(F(30), wgu, 1536, 128, 3072, 1, 2, 1179648);
    CP(F(31), wdnb, 1179648);
    cast6<<<768, 256, 0, stream>>>(F(3), F(4), F(5), F(6), F(8), F(12), wdR);
    CP(F(10), woutR, 32768);
    cast6<<<768, 256, 0, stream>>>(F(13), F(14), F(15), F(16), F(18), F(22), wdW);
    CP(F(20), woutW, 32768);
    cast_embed_pad<<<64, 256, 0, stream>>>(embedw, embp);

    rope_tables_k<<<128, 256, 0, stream>>>(cosT, sinT);
    embed_k<<<4096, 128, 0, stream>>>(ids, embedw, H);

    // ---- delta read ----
    CP(H, Hbf, 524288);
    G(0, Hbf, wdR, P, nullptr, 4096, 1536, 512, 1536);
    delta_scan<<<16, 64, 0, stream>>>(P, state, F(7), F(9), Sbuf, ctxf);
    ctx_post<<<4096, 64, 0, stream>>>(ctxf, P, F(11), ctxb);
    G(1, ctxb, woutR, H, nullptr, 4096, 512, 256, 512);

    for (int i = 0; i < 6; ++i) {
        rmsnorm512<<<4096, 128, 0, stream>>>(H, F(23) + (size_t)i * 512, XNbf);
        G(0, XNbf, wqkv + (size_t)i * 1536 * 512, P, nullptr, 4096, 1536, 512, 1536);
        qkv_prep<<<4096, 256, 0, stream>>>(P, cosT, sinT, Qbuf, Kbuf, Vtb);
        attn_mfma<<<dim3(16, 8, 4), 256, 0, stream>>>(Qbuf, Kbuf, Vtb, Obf);
        G(1, Obf, wob + (size_t)i * 512 * 512, H, nullptr, 4096, 512, 512, 512);
        rmsnorm512<<<4096, 128, 0, stream>>>(H, F(28) + (size_t)i * 512, XNbf);
        G(4, XNbf, wgu + (size_t)i * 3072 * 512, nullptr, A1b, 4096, 3072, 512, 1536);
        G(1, A1b, wdnb + (size_t)i * 512 * 1536, H, nullptr, 4096, 512, 1536, 512);
    }

    // ---- delta write ----
    CP(H, Hbf, 524288);
    G(0, Hbf, wdW, P, nullptr, 4096, 1536, 512, 1536);
    delta_scan<<<16, 64, 0, stream>>>(P, Sbuf, F(17), F(19), Sout, ctxf);
    ctx_post<<<4096, 64, 0, stream>>>(ctxf, P, F(21), ctxb);
    G(1, ctxb, woutW, H, nullptr, 4096, 512, 256, 512);

    rmsnorm512<<<4096, 128, 0, stream>>>(H, F(32), XNbf);
    G(0, XNbf, embp, logits, nullptr, 4096, 128, 512, VOCN);
}

// Round 6
// 2018.603 us; speedup vs baseline: 1.2335x; 1.2335x over previous
//
#include <hip/hip_runtime.h>
#include <hip/hip_bf16.h>
#include <math.h>

// ---------------------------------------------------------------------------
// BashTransformer forward on MI355X. Round 6: delta scan with pair-split rows
// (16 S elems/lane), DPP-based pair reduction (VALU pipe, no lgkmcnt drain),
// branchless 16-step descale. Fused silu GEMM, MFMA flash attn, bf16 GEMMs.
// ---------------------------------------------------------------------------

#define LSEQ 1024
#define BATCH 4
#define HIDDEN 512
#define NHEAD 8
#define HDIM 64
#define SHEAD 8
#define SDHD 32
#define SDIMM 256
#define FFND 1536
#define VOCN 63
#define ATTS 72   // attn LDS row stride (elems): 144B = 16B-aligned, 2-way banks

typedef __bf16 bf16;
typedef __attribute__((ext_vector_type(8))) __bf16 bf16x8;
typedef __attribute__((ext_vector_type(4))) float floatx4;

union BF4 { bf16 h[4]; short4 p; };

__device__ __forceinline__ void gload16(const void* g, const void* l) {
    __builtin_amdgcn_global_load_lds(
        (__attribute__((address_space(1))) unsigned int*)(uintptr_t)g,
        (__attribute__((address_space(3))) unsigned int*)(unsigned int)(uintptr_t)l,
        16, 0, 0);
}

// pair sum via DPP quad_perm [1,0,3,2] — VALU pipe, no LDS counter involved
__device__ __forceinline__ float pair_add(float x) {
    int sw = __builtin_amdgcn_mov_dpp(__float_as_int(x), 0xB1, 0xF, 0xF, true);
    return x + __int_as_float(sw);
}

// ------------------------------- rope tables -------------------------------
__global__ void rope_tables_k(float* __restrict__ cosT, float* __restrict__ sinT) {
    int idx = blockIdx.x * 256 + threadIdx.x;   // 32768 = 1024*32
    int l = idx >> 5, d = idx & 31;
    double ang = (double)l * pow(500000.0, -(double)(2 * d) / 64.0);
    cosT[idx] = (float)cos(ang);
    sinT[idx] = (float)sin(ang);
}

// ------------------------------- embedding ---------------------------------
__global__ void embed_k(const int* __restrict__ ids, const float* __restrict__ emb,
                        float* __restrict__ h) {
    int tok = blockIdx.x;
    int id = ids[tok];
    ((float4*)(h + (size_t)tok * HIDDEN))[threadIdx.x] =
        ((const float4*)(emb + (size_t)id * HIDDEN))[threadIdx.x];
}

// ------------------------------- casts -------------------------------------
__global__ void cast_plain(const float* __restrict__ s, bf16* __restrict__ d, int n4) {
    int i = blockIdx.x * 256 + threadIdx.x;
    if (i >= n4) return;
    float4 v = ((const float4*)s)[i];
    BF4 u;
    u.h[0] = (bf16)v.x; u.h[1] = (bf16)v.y; u.h[2] = (bf16)v.z; u.h[3] = (bf16)v.w;
    ((short4*)d)[i] = u.p;
}

// six 256x512 f32 matrices -> one fused 1536x512 bf16 (order s0..s5)
__global__ void cast6(const float* s0, const float* s1, const float* s2,
                      const float* s3, const float* s4, const float* s5,
                      bf16* __restrict__ d) {
    int i = blockIdx.x * 256 + threadIdx.x;      // 196608 short4s
    if (i >= 196608) return;
    int which = i >> 15, loc = i & 32767;
    const float* s = which == 0 ? s0 : which == 1 ? s1 : which == 2 ? s2
                    : which == 3 ? s3 : which == 4 ? s4 : s5;
    float4 v = ((const float4*)s)[loc];
    BF4 u;
    u.h[0] = (bf16)v.x; u.h[1] = (bf16)v.y; u.h[2] = (bf16)v.z; u.h[3] = (bf16)v.w;
    ((short4*)d)[i] = u.p;
}

// gather (layers,R,K) f32 -> fused bf16 rows [i*dstStride + dstOff + r*rowMul]
__global__ void cast_fuse(const float* __restrict__ s, bf16* __restrict__ d,
                          int R, int K4, int dstStride, int dstOff, int rowMul,
                          int total4) {
    int idx = blockIdx.x * 256 + threadIdx.x;
    if (idx >= total4) return;
    int perLayer = R * K4;
    int i = idx / perLayer;
    int rem = idx - i * perLayer;
    int r = rem / K4, c4 = rem - r * K4;
    float4 v = ((const float4*)s)[idx];
    BF4 u;
    u.h[0] = (bf16)v.x; u.h[1] = (bf16)v.y; u.h[2] = (bf16)v.z; u.h[3] = (bf16)v.w;
    ((short4*)d)[((size_t)i * dstStride + dstOff + r * rowMul) * K4 + c4] = u.p;
}

__global__ void cast_embed_pad(const float* __restrict__ s, bf16* __restrict__ d) {
    int i = blockIdx.x * 256 + threadIdx.x;   // 128*128 = 16384 short4s
    int row = i >> 7, c4 = i & 127;
    BF4 u;
    if (row < VOCN) {
        float4 v = ((const float4*)s)[row * 128 + c4];
        u.h[0] = (bf16)v.x; u.h[1] = (bf16)v.y; u.h[2] = (bf16)v.z; u.h[3] = (bf16)v.w;
    } else {
        u.h[0] = (bf16)0.f; u.h[1] = (bf16)0.f; u.h[2] = (bf16)0.f; u.h[3] = (bf16)0.f;
    }
    ((short4*)d)[i] = u.p;
}

// ------------------------------- rmsnorm -> bf16 ---------------------------
__global__ void rmsnorm512(const float* __restrict__ in, const float* __restrict__ w,
                           bf16* __restrict__ out) {
    int row = blockIdx.x, t = threadIdx.x;     // 128 threads
    float4 x = ((const float4*)(in + (size_t)row * 512))[t];
    float s = x.x * x.x + x.y * x.y + x.z * x.z + x.w * x.w;
    for (int m = 1; m < 64; m <<= 1) s += __shfl_xor(s, m);
    __shared__ float red[2];
    if ((t & 63) == 0) red[t >> 6] = s;
    __syncthreads();
    float tot = red[0] + red[1];
    float r = rsqrtf(tot * (1.f / 512.f) + 1e-6f);
    float4 wv = ((const float4*)w)[t];
    BF4 u;
    u.h[0] = (bf16)(x.x * r * wv.x); u.h[1] = (bf16)(x.y * r * wv.y);
    u.h[2] = (bf16)(x.z * r * wv.z); u.h[3] = (bf16)(x.w * r * wv.w);
    ((short4*)(out + (size_t)row * 512))[t] = u.p;
}

// ------------------------------- bf16 MFMA GEMM ----------------------------
// C = A(bf16, MxK rm) @ B(bf16, NxK rm)^T. 128x128 tile, Kstep 32, 4 waves.
// MODE 0: C(f32)=v  MODE 1: C(f32)+=v
// MODE 4: gate/up interleaved cols; Cb[row*Nreal+col/2]=bf16(silu(g)*u).
template <int MODE>
__global__ __launch_bounds__(256) void gemm_bf16(const bf16* __restrict__ A,
                                                 const bf16* __restrict__ B,
                                                 float* __restrict__ C,
                                                 bf16* __restrict__ Cb,
                                                 int M, int N, int K, int Nreal) {
    __shared__ bf16 As[128 * 32];
    __shared__ bf16 Bs[128 * 32];
    const int tid = threadIdx.x;
    const int wave = tid >> 6, lane = tid & 63;
    const int row0 = blockIdx.y * 128, col0 = blockIdx.x * 128;
    floatx4 acc[4][4];
#pragma unroll
    for (int i = 0; i < 4; ++i)
#pragma unroll
        for (int j = 0; j < 4; ++j) acc[i][j] = (floatx4){0.f, 0.f, 0.f, 0.f};
    const int m0 = (wave & 1) * 64, n0 = (wave >> 1) * 64;
    const int sr = tid >> 2;
    const int ske = (tid & 3) * 8;
    const size_t arow1 = (size_t)(row0 + sr) * K + ske;
    const size_t arow2 = (size_t)(row0 + 64 + sr) * K + ske;
    const size_t brow1 = (size_t)(col0 + sr) * K + ske;
    const size_t brow2 = (size_t)(col0 + 64 + sr) * K + ske;
    char* AsB = (char*)As;
    char* BsB = (char*)Bs;
    const int lds0 = wave * 1024, lds1 = 4096 + wave * 1024;

    for (int k0 = 0; k0 < K; k0 += 32) {
        gload16(A + arow1 + k0, AsB + lds0);
        gload16(A + arow2 + k0, AsB + lds1);
        gload16(B + brow1 + k0, BsB + lds0);
        gload16(B + brow2 + k0, BsB + lds1);
        __syncthreads();
        bf16x8 af[4], bfr[4];
#pragma unroll
        for (int mi = 0; mi < 4; ++mi)
            af[mi] = *(const bf16x8*)(AsB + ((m0 + mi * 16 + (lane & 15)) * 32 + (lane >> 4) * 8) * 2);
#pragma unroll
        for (int ni = 0; ni < 4; ++ni)
            bfr[ni] = *(const bf16x8*)(BsB + ((n0 + ni * 16 + (lane & 15)) * 32 + (lane >> 4) * 8) * 2);
#pragma unroll
        for (int mi = 0; mi < 4; ++mi)
#pragma unroll
            for (int ni = 0; ni < 4; ++ni)
                acc[mi][ni] = __builtin_amdgcn_mfma_f32_16x16x32_bf16(af[mi], bfr[ni], acc[mi][ni], 0, 0, 0);
        __syncthreads();
    }
    const int cr = (lane >> 4) * 4;
    const int cc = lane & 15;
#pragma unroll
    for (int mi = 0; mi < 4; ++mi) {
#pragma unroll
        for (int ni = 0; ni < 4; ++ni) {
#pragma unroll
            for (int r = 0; r < 4; ++r) {
                int row = row0 + m0 + mi * 16 + cr + r;
                int col = col0 + n0 + ni * 16 + cc;
                float v = acc[mi][ni][r];
                if (MODE == 4) {
                    float o = __shfl_xor(v, 1);
                    if (!(lane & 1)) {
                        float sg = v / (1.f + __expf(-v));
                        Cb[(size_t)row * Nreal + (col >> 1)] = (bf16)(sg * o);
                    }
                } else if (col < Nreal) {
                    size_t off = (size_t)row * Nreal + col;
                    if (MODE == 0) C[off] = v;
                    else if (MODE == 1) C[off] += v;
                }
            }
        }
    }
}

// ----------------- QKV prep: RoPE + bf16 cast + V transpose ----------------
__global__ void qkv_prep(const float* __restrict__ P, const float* __restrict__ cosT,
                         const float* __restrict__ sinT, bf16* __restrict__ Qb,
                         bf16* __restrict__ Kb, bf16* __restrict__ Vtb) {
    int tok = blockIdx.x;                       // 4096
    int b = tok >> 10, l = tok & 1023;
    int hh = threadIdx.x >> 5, d = threadIdx.x & 31;
    const float* q = P + (size_t)tok * 1536 + hh * 64;
    const float* k = q + 512;
    const float* v = q + 1024;
    float c = cosT[l * 32 + d], s = sinT[l * 32 + d];
    size_t base = ((size_t)(b * 8 + hh) * 1024 + l) * 64;
    float q1 = q[d], q2 = q[d + 32];
    Qb[base + d] = (bf16)(q1 * c - q2 * s);
    Qb[base + d + 32] = (bf16)(q2 * c + q1 * s);
    float k1 = k[d], k2 = k[d + 32];
    Kb[base + d] = (bf16)(k1 * c - k2 * s);
    Kb[base + d + 32] = (bf16)(k2 * c + k1 * s);
    size_t vb = (size_t)(b * 8 + hh) * 64 * 1024 + l;
    Vtb[vb + (size_t)d * 1024] = (bf16)v[d];
    Vtb[vb + (size_t)(d + 32) * 1024] = (bf16)v[d + 32];
}

// ------------------------- MFMA flash attention ----------------------------
__global__ __launch_bounds__(256) void attn_mfma(const bf16* __restrict__ Qb,
                                                 const bf16* __restrict__ Kb,
                                                 const bf16* __restrict__ Vtb,
                                                 bf16* __restrict__ O) {
    int qt = blockIdx.x, hh = blockIdx.y, b = blockIdx.z;
    int bh = b * 8 + hh;
    int q0 = qt * 64;
    const bf16* Qg = Qb + ((size_t)bh * 1024 + q0) * 64;
    const bf16* Kg = Kb + (size_t)bh * 1024 * 64;
    const bf16* Vg = Vtb + (size_t)bh * 64 * 1024;   // [64 d][1024 l]
    __shared__ bf16 Qs[64 * ATTS];
    __shared__ bf16 Ks[64 * ATTS];
    __shared__ bf16 Vs[64 * ATTS];
    __shared__ bf16 Ps[64 * ATTS];
    int tid = threadIdx.x, wave = tid >> 6, lane = tid & 63;
    int lr = lane & 15, quad = lane >> 4;

#pragma unroll
    for (int it = 0; it < 2; ++it) {
        int cidx = tid + it * 256;
        int row = cidx >> 3, ch = cidx & 7;
        *(bf16x8*)(Qs + row * ATTS + ch * 8) = *(const bf16x8*)(Qg + row * 64 + ch * 8);
    }
    float mrow[4], lrow[4];
    floatx4 Oacc[4];
#pragma unroll
    for (int r = 0; r < 4; ++r) { mrow[r] = -1e30f; lrow[r] = 0.f; }
#pragma unroll
    for (int d0 = 0; d0 < 4; ++d0) Oacc[d0] = (floatx4){0.f, 0.f, 0.f, 0.f};

    int ntiles = qt + 1;
    for (int t = 0; t < ntiles; ++t) {
        int kv0 = t * 64;
        __syncthreads();
#pragma unroll
        for (int it = 0; it < 2; ++it) {
            int cidx = tid + it * 256;
            int row = cidx >> 3, ch = cidx & 7;
            *(bf16x8*)(Ks + row * ATTS + ch * 8) =
                *(const bf16x8*)(Kg + (size_t)(kv0 + row) * 64 + ch * 8);
            *(bf16x8*)(Vs + row * ATTS + ch * 8) =
                *(const bf16x8*)(Vg + (size_t)row * 1024 + kv0 + ch * 8);
        }
        __syncthreads();
        bf16x8 aq[2];
#pragma unroll
        for (int kc = 0; kc < 2; ++kc)
            aq[kc] = *(const bf16x8*)(Qs + (wave * 16 + lr) * ATTS + kc * 32 + quad * 8);
        floatx4 sacc[4];
#pragma unroll
        for (int n0 = 0; n0 < 4; ++n0) {
            bf16x8 bk0 = *(const bf16x8*)(Ks + (n0 * 16 + lr) * ATTS + quad * 8);
            bf16x8 bk1 = *(const bf16x8*)(Ks + (n0 * 16 + lr) * ATTS + 32 + quad * 8);
            floatx4 z = (floatx4){0.f, 0.f, 0.f, 0.f};
            z = __builtin_amdgcn_mfma_f32_16x16x32_bf16(aq[0], bk0, z, 0, 0, 0);
            sacc[n0] = __builtin_amdgcn_mfma_f32_16x16x32_bf16(aq[1], bk1, z, 0, 0, 0);
        }
        float sv[4][4];
#pragma unroll
        for (int n0 = 0; n0 < 4; ++n0)
#pragma unroll
            for (int r = 0; r < 4; ++r) sv[n0][r] = sacc[n0][r] * 0.125f;
        if (t == ntiles - 1) {
#pragma unroll
            for (int n0 = 0; n0 < 4; ++n0)
#pragma unroll
                for (int r = 0; r < 4; ++r)
                    if (n0 * 16 + lr > wave * 16 + quad * 4 + r) sv[n0][r] = -1e30f;
        }
        float al[4];
#pragma unroll
        for (int r = 0; r < 4; ++r) {
            float tm = fmaxf(fmaxf(sv[0][r], sv[1][r]), fmaxf(sv[2][r], sv[3][r]));
            tm = fmaxf(tm, __shfl_xor(tm, 1));
            tm = fmaxf(tm, __shfl_xor(tm, 2));
            tm = fmaxf(tm, __shfl_xor(tm, 4));
            tm = fmaxf(tm, __shfl_xor(tm, 8));
            float mn = fmaxf(mrow[r], tm);
            al[r] = __expf(mrow[r] - mn);
            mrow[r] = mn;
        }
        float rs[4];
#pragma unroll
        for (int r = 0; r < 4; ++r) rs[r] = 0.f;
#pragma unroll
        for (int n0 = 0; n0 < 4; ++n0)
#pragma unroll
            for (int r = 0; r < 4; ++r) {
                float p = __expf(sv[n0][r] - mrow[r]);
                sv[n0][r] = p;
                rs[r] += p;
            }
#pragma unroll
        for (int r = 0; r < 4; ++r) {
            float t2 = rs[r];
            t2 += __shfl_xor(t2, 1);
            t2 += __shfl_xor(t2, 2);
            t2 += __shfl_xor(t2, 4);
            t2 += __shfl_xor(t2, 8);
            lrow[r] = lrow[r] * al[r] + t2;
        }
#pragma unroll
        for (int d0 = 0; d0 < 4; ++d0)
#pragma unroll
            for (int r = 0; r < 4; ++r) Oacc[d0][r] *= al[r];
#pragma unroll
        for (int n0 = 0; n0 < 4; ++n0)
#pragma unroll
            for (int r = 0; r < 4; ++r)
                Ps[(wave * 16 + quad * 4 + r) * ATTS + n0 * 16 + lr] = (bf16)sv[n0][r];
        bf16x8 ap[2];
#pragma unroll
        for (int kc = 0; kc < 2; ++kc)
            ap[kc] = *(const bf16x8*)(Ps + (wave * 16 + lr) * ATTS + kc * 32 + quad * 8);
#pragma unroll
        for (int d0 = 0; d0 < 4; ++d0) {
            bf16x8 bv0 = *(const bf16x8*)(Vs + (d0 * 16 + lr) * ATTS + quad * 8);
            bf16x8 bv1 = *(const bf16x8*)(Vs + (d0 * 16 + lr) * ATTS + 32 + quad * 8);
            Oacc[d0] = __builtin_amdgcn_mfma_f32_16x16x32_bf16(ap[0], bv0, Oacc[d0], 0, 0, 0);
            Oacc[d0] = __builtin_amdgcn_mfma_f32_16x16x32_bf16(ap[1], bv1, Oacc[d0], 0, 0, 0);
        }
    }
    float inv[4];
#pragma unroll
    for (int r = 0; r < 4; ++r) inv[r] = 1.f / lrow[r];
#pragma unroll
    for (int d0 = 0; d0 < 4; ++d0)
#pragma unroll
        for (int r = 0; r < 4; ++r) {
            int row = b * 1024 + q0 + wave * 16 + quad * 4 + r;
            int col = hh * 64 + d0 * 16 + lr;
            O[(size_t)row * 512 + col] = (bf16)(Oacc[d0][r] * inv[r]);
        }
}

// ------------------------------- delta scan --------------------------------
// 32 blocks x 1 wave; lane = (row i = lane>>1, half hf = lane&1) owns 16 S
// elems. Pair reduction via DPP (VALU pipe — LDS prefetch stays in flight).
// Descaled state S_real = D * S; branchless rescale every 16 steps.
__global__ __launch_bounds__(64, 1) void delta_scan(
    const float* __restrict__ P, const float* __restrict__ S_in,
    const float* __restrict__ bbias, const float* __restrict__ abias,
    float* __restrict__ S_out, float* __restrict__ ctx) {
    int bh = blockIdx.x;
    int b = bh >> 3, hh = bh & 7;
    int lane = threadIdx.x;
    int i = lane >> 1, hf = lane & 1;
    __shared__ float ks[66][36], qs[66][36], vs[66][36], bs[66][36], as_[66][36];
    float4 S[4];
    {
        const float4* Sp = (const float4*)(S_in + ((size_t)bh * 32 + i) * 32 + hf * 16);
#pragma unroll
        for (int m = 0; m < 4; ++m) S[m] = Sp[m];
    }
    int c4 = lane & 7, r0 = lane >> 3;
    float4 bB = *(const float4*)(bbias + hh * 32 + c4 * 4);
    float4 bA = *(const float4*)(abias + hh * 32 + c4 * 4);
    float D = 1.f, Dinv = 1.f;

    float4 ka[4], qa[4], kb[4], qb[4];
    float aa, ba, va, a2, b2, v2;

    auto loadt = [&](int tt, float4* kk, float4* qq, float& ax, float& bx, float& vx) {
        const float* kr = &ks[tt][hf * 16];
        const float* qr = &qs[tt][hf * 16];
#pragma unroll
        for (int j4 = 0; j4 < 4; ++j4) {
            kk[j4] = *(const float4*)(kr + j4 * 4);
            qq[j4] = *(const float4*)(qr + j4 * 4);
        }
        ax = as_[tt][i]; bx = bs[tt][i]; vx = vs[tt][i];
    };
    auto stepf = [&](const float4* kk, const float4* qq, float ax, float bx, float vx,
                     int gtok) {
        float d0 = fmaf(S[0].w, kk[0].w, fmaf(S[0].z, kk[0].z,
                   fmaf(S[0].y, kk[0].y, S[0].x * kk[0].x)));
        float d1 = fmaf(S[1].w, kk[1].w, fmaf(S[1].z, kk[1].z,
                   fmaf(S[1].y, kk[1].y, S[1].x * kk[1].x)));
        float d2 = fmaf(S[2].w, kk[2].w, fmaf(S[2].z, kk[2].z,
                   fmaf(S[2].y, kk[2].y, S[2].x * kk[2].x)));
        float d3 = fmaf(S[3].w, kk[3].w, fmaf(S[3].z, kk[3].z,
                   fmaf(S[3].y, kk[3].y, S[3].x * kk[3].x)));
        float dot = pair_add((d0 + d1) + (d2 + d3));
        float u = bx * (vx - ax * (D * dot));
        D *= ax;
        Dinv *= __builtin_amdgcn_rcpf(ax);
        float ud = u * Dinv;
#pragma unroll
        for (int m = 0; m < 4; ++m) {
            S[m].x = fmaf(ud, kk[m].x, S[m].x);
            S[m].y = fmaf(ud, kk[m].y, S[m].y);
            S[m].z = fmaf(ud, kk[m].z, S[m].z);
            S[m].w = fmaf(ud, kk[m].w, S[m].w);
        }
        float e0 = fmaf(S[0].w, qq[0].w, fmaf(S[0].z, qq[0].z,
                   fmaf(S[0].y, qq[0].y, S[0].x * qq[0].x)));
        float e1 = fmaf(S[1].w, qq[1].w, fmaf(S[1].z, qq[1].z,
                   fmaf(S[1].y, qq[1].y, S[1].x * qq[1].x)));
        float e2 = fmaf(S[2].w, qq[2].w, fmaf(S[2].z, qq[2].z,
                   fmaf(S[2].y, qq[2].y, S[2].x * qq[2].x)));
        float e3 = fmaf(S[3].w, qq[3].w, fmaf(S[3].z, qq[3].z,
                   fmaf(S[3].y, qq[3].y, S[3].x * qq[3].x)));
        float rd = pair_add((e0 + e1) + (e2 + e3));
        // both lanes of pair write same addr+value (no branch)
        ctx[(size_t)gtok * 256 + hh * 32 + i] = D * rd;
    };

    for (int c0 = 0; c0 < LSEQ; c0 += 64) {
        __syncthreads();
        const float* Pb = P + ((size_t)(b * 1024 + c0) * 1536) + hh * 32 + c4 * 4;
#pragma unroll
        for (int it = 0; it < 8; ++it) {
            int row = r0 + it * 8;
            const float* pg = Pb + (size_t)row * 1536;
            float4 kv = *(const float4*)(pg);
            float4 vv = *(const float4*)(pg + 256);
            float4 qv = *(const float4*)(pg + 512);
            float4 bv = *(const float4*)(pg + 768);
            float4 av = *(const float4*)(pg + 1024);
            // k row-norm across the 8-lane group holding this row
            float ss = kv.x * kv.x + kv.y * kv.y + kv.z * kv.z + kv.w * kv.w;
            ss += __shfl_xor(ss, 1);
            ss += __shfl_xor(ss, 2);
            ss += __shfl_xor(ss, 4);
            float rn = 1.f / fmaxf(sqrtf(ss), 1e-12f);
            kv.x *= rn; kv.y *= rn; kv.z *= rn; kv.w *= rn;
            *(float4*)&ks[row][c4 * 4] = kv;
            *(float4*)&vs[row][c4 * 4] = vv;
            *(float4*)&qs[row][c4 * 4] = qv;
            float4 bo, ao;
            bo.x = 1.f / (1.f + __expf(-(bv.x + bB.x)));
            bo.y = 1.f / (1.f + __expf(-(bv.y + bB.y)));
            bo.z = 1.f / (1.f + __expf(-(bv.z + bB.z)));
            bo.w = 1.f / (1.f + __expf(-(bv.w + bB.w)));
            ao.x = 1.f / (1.f + __expf(-(av.x + bA.x)));
            ao.y = 1.f / (1.f + __expf(-(av.y + bA.y)));
            ao.z = 1.f / (1.f + __expf(-(av.z + bA.z)));
            ao.w = 1.f / (1.f + __expf(-(av.w + bA.w)));
            *(float4*)&bs[row][c4 * 4] = bo;
            *(float4*)&as_[row][c4 * 4] = ao;
        }
        __syncthreads();
        int gbase = b * 1024 + c0;
#pragma unroll
        for (int sb = 0; sb < 4; ++sb) {
            int t0 = sb * 16;
            loadt(t0, ka, qa, aa, ba, va);
            for (int t = 0; t < 16; t += 2) {
                loadt(t0 + t + 1, kb, qb, a2, b2, v2);
                stepf(ka, qa, aa, ba, va, gbase + t0 + t);
                loadt(t0 + t + 2, ka, qa, aa, ba, va);   // row<=64 padded
                stepf(kb, qb, a2, b2, v2, gbase + t0 + t + 1);
            }
            // branchless rescale every 16 steps
#pragma unroll
            for (int m = 0; m < 4; ++m) {
                S[m].x *= D; S[m].y *= D; S[m].z *= D; S[m].w *= D;
            }
            D = 1.f; Dinv = 1.f;
        }
    }
    float4* So = (float4*)(S_out + ((size_t)bh * 32 + i) * 32 + hf * 16);
#pragma unroll
    for (int m = 0; m < 4; ++m) So[m] = S[m];
}

// ------------- ctxbf = bf16(rmsnorm(ctx,nw)*silu(gate)), gate in P@1280 ----
__global__ void ctx_post(const float* __restrict__ ctx, const float* __restrict__ P,
                         const float* __restrict__ nw, bf16* __restrict__ out) {
    int row = blockIdx.x, t = threadIdx.x;  // 64 threads
    float4 x = ((const float4*)(ctx + (size_t)row * SDIMM))[t];
    float s = x.x * x.x + x.y * x.y + x.z * x.z + x.w * x.w;
    for (int m = 1; m < 64; m <<= 1) s += __shfl_xor(s, m);
    float r = rsqrtf(s * (1.f / 256.f) + 1e-6f);
    float4 n = ((const float4*)nw)[t];
    float4 g = ((const float4*)(P + (size_t)row * 1536 + 1280))[t];
    BF4 u;
    u.h[0] = (bf16)(x.x * r * n.x * (g.x / (1.f + __expf(-g.x))));
    u.h[1] = (bf16)(x.y * r * n.y * (g.y / (1.f + __expf(-g.y))));
    u.h[2] = (bf16)(x.z * r * n.z * (g.z / (1.f + __expf(-g.z))));
    u.h[3] = (bf16)(x.w * r * n.w * (g.w / (1.f + __expf(-g.w))));
    ((short4*)(out + (size_t)row * SDIMM))[t] = u.p;
}

// ---------------------------------------------------------------------------
extern "C" void kernel_launch(void* const* d_in, const int* in_sizes, int n_in,
                              void* d_out, int out_size, void* d_ws, size_t ws_size,
                              hipStream_t stream) {
    (void)in_sizes; (void)n_in; (void)out_size; (void)ws_size;
    const int* ids = (const int*)d_in[0];
    const float* state = (const float*)d_in[1];
    const float* embedw = (const float*)d_in[2];
    auto F = [&](int i) { return (const float*)d_in[i]; };

    char* wsb = (char*)d_ws;
    const size_t MB = 1048576;
    float* H    = (float*)(wsb);                 // 0-8 MB
    bf16*  XNbf = (bf16*)(wsb + 8 * MB);         // 8-12 (alias ctxf in delta)
    float* ctxf = (float*)(wsb + 8 * MB);
    bf16*  Hbf  = (bf16*)(wsb + 12 * MB);        // 12-16 (alias ctxb)
    bf16*  ctxb = (bf16*)(wsb + 12 * MB);
    float* P    = (float*)(wsb + 16 * MB);       // 16-40 (QKV f32 / delta f32)
    bf16*  Obf  = (bf16*)(wsb + 40 * MB);        // 40-44 attn out
    bf16*  Qbuf = (bf16*)(wsb + 44 * MB);        // 44-48
    bf16*  Kbuf = (bf16*)(wsb + 48 * MB);        // 48-52
    bf16*  Vtb  = (bf16*)(wsb + 52 * MB);        // 52-56
    bf16*  A1b  = (bf16*)(wsb + 44 * MB);        // alias Q/K/Vt (dead after attn)
    float* cosT = (float*)(wsb + 58 * MB);
    float* sinT = cosT + 32768;
    float* Sbuf = sinT + 32768;
    char*  wbase = wsb + 59 * MB;
    bf16* wqkv  = (bf16*)(wbase);                        // 6x1536x512
    bf16* wob   = (bf16*)(wbase + 9437184);              // 6x512x512
    bf16* wgu   = (bf16*)(wbase + 12582912);             // 6x3072x512 interleaved
    bf16* wdnb  = (bf16*)(wbase + 31457280);             // 6x512x1536
    bf16* wdR   = (bf16*)(wbase + 40894464);             // 1536x512
    bf16* woutR = (bf16*)(wbase + 42467328);             // 512x256
    bf16* wdW   = (bf16*)(wbase + 42729472);             // 1536x512
    bf16* woutW = (bf16*)(wbase + 44302336);             // 512x256
    bf16* embp  = (bf16*)(wbase + 44564480);             // 128x512 padded

    float* out = (float*)d_out;
    float* logits = out;
    float* Sout = out + 4096 * VOCN;

    auto G = [&](int mode, const bf16* A, const bf16* B, float* C, bf16* Cb,
                 int M, int N, int K, int Nreal) {
        dim3 grid(N / 128, M / 128);
        if (mode == 0) gemm_bf16<0><<<grid, 256, 0, stream>>>(A, B, C, Cb, M, N, K, Nreal);
        else if (mode == 1) gemm_bf16<1><<<grid, 256, 0, stream>>>(A, B, C, Cb, M, N, K, Nreal);
        else gemm_bf16<4><<<grid, 256, 0, stream>>>(A, B, C, Cb, M, N, K, Nreal);
    };
    auto CP = [&](const float* s, bf16* d, int n4) {
        cast_plain<<<(n4 + 255) / 256, 256, 0, stream>>>(s, d, n4);
    };

    // ---- weight casts ----
    cast_fuse<<<1536, 256, 0, stream>>>(F(24), wqkv, 512, 128, 1536, 0, 1, 393216);
    cast_fuse<<<1536, 256, 0, stream>>>(F(25), wqkv, 512, 128, 1536, 512, 1, 393216);
    cast_fuse<<<1536, 256, 0, stream>>>(F(26), wqkv, 512, 128, 1536, 1024, 1, 393216);
    CP(F(27), wob, 393216);
    cast_fuse<<<4608, 256, 0, stream>>>(F(29), wgu, 1536, 128, 3072, 0, 2, 1179648);
    cast_fuse<<<4608, 256, 0, stream>>>(F(30), wgu, 1536, 128, 3072, 1, 2, 1179648);
    CP(F(31), wdnb, 1179648);
    cast6<<<768, 256, 0, stream>>>(F(3), F(4), F(5), F(6), F(8), F(12), wdR);
    CP(F(10), woutR, 32768);
    cast6<<<768, 256, 0, stream>>>(F(13), F(14), F(15), F(16), F(18), F(22), wdW);
    CP(F(20), woutW, 32768);
    cast_embed_pad<<<64, 256, 0, stream>>>(embedw, embp);

    rope_tables_k<<<128, 256, 0, stream>>>(cosT, sinT);
    embed_k<<<4096, 128, 0, stream>>>(ids, embedw, H);

    // ---- delta read ----
    CP(H, Hbf, 524288);
    G(0, Hbf, wdR, P, nullptr, 4096, 1536, 512, 1536);
    delta_scan<<<32, 64, 0, stream>>>(P, state, F(7), F(9), Sbuf, ctxf);
    ctx_post<<<4096, 64, 0, stream>>>(ctxf, P, F(11), ctxb);
    G(1, ctxb, woutR, H, nullptr, 4096, 512, 256, 512);

    for (int i = 0; i < 6; ++i) {
        rmsnorm512<<<4096, 128, 0, stream>>>(H, F(23) + (size_t)i * 512, XNbf);
        G(0, XNbf, wqkv + (size_t)i * 1536 * 512, P, nullptr, 4096, 1536, 512, 1536);
        qkv_prep<<<4096, 256, 0, stream>>>(P, cosT, sinT, Qbuf, Kbuf, Vtb);
        attn_mfma<<<dim3(16, 8, 4), 256, 0, stream>>>(Qbuf, Kbuf, Vtb, Obf);
        G(1, Obf, wob + (size_t)i * 512 * 512, H, nullptr, 4096, 512, 512, 512);
        rmsnorm512<<<4096, 128, 0, stream>>>(H, F(28) + (size_t)i * 512, XNbf);
        G(4, XNbf, wgu + (size_t)i * 3072 * 512, nullptr, A1b, 4096, 3072, 512, 1536);
        G(1, A1b, wdnb + (size_t)i * 512 * 1536, H, nullptr, 4096, 512, 1536, 512);
    }

    // ---- delta write ----
    CP(H, Hbf, 524288);
    G(0, Hbf, wdW, P, nullptr, 4096, 1536, 512, 1536);
    delta_scan<<<32, 64, 0, stream>>>(P, Sbuf, F(17), F(19), Sout, ctxf);
    ctx_post<<<4096, 64, 0, stream>>>(ctxf, P, F(21), ctxb);
    G(1, ctxb, woutW, H, nullptr, 4096, 512, 256, 512);

    rmsnorm512<<<4096, 128, 0, stream>>>(H, F(32), XNbf);
    G(0, XNbf, embp, logits, nullptr, 4096, 128, 512, VOCN);
}

// Round 7
// 1680.969 us; speedup vs baseline: 1.4812x; 1.2009x over previous
//
#include <hip/hip_runtime.h>
#include <hip/hip_bf16.h>
#include <math.h>

// ---------------------------------------------------------------------------
// BashTransformer forward on MI355X. Round 7: delta scan with 4-wave row
// parallelism (S row slice per lane, DPP sum8 reductions, LDS ctx staging,
// no intra-chunk syncs). Fused silu GEMM, MFMA flash attn, bf16 MFMA GEMMs.
// ---------------------------------------------------------------------------

#define LSEQ 1024
#define BATCH 4
#define HIDDEN 512
#define NHEAD 8
#define HDIM 64
#define SHEAD 8
#define SDHD 32
#define SDIMM 256
#define FFND 1536
#define VOCN 63
#define ATTS 72   // attn LDS row stride (elems): 144B = 16B-aligned, 2-way banks

typedef __bf16 bf16;
typedef __attribute__((ext_vector_type(8))) __bf16 bf16x8;
typedef __attribute__((ext_vector_type(4))) float floatx4;

union BF4 { bf16 h[4]; short4 p; };

__device__ __forceinline__ void gload16(const void* g, const void* l) {
    __builtin_amdgcn_global_load_lds(
        (__attribute__((address_space(1))) unsigned int*)(uintptr_t)g,
        (__attribute__((address_space(3))) unsigned int*)(unsigned int)(uintptr_t)l,
        16, 0, 0);
}

// sum over aligned groups of 8 lanes, pure DPP (VALU pipe, no LDS counters):
// xor1 = quad_perm [1,0,3,2] (0xB1), xor2 = quad_perm [2,3,0,1] (0x4E),
// xor4 within 8 = row_half_mirror (0x141). All lanes end with the group sum.
__device__ __forceinline__ float sum8(float x) {
    x += __int_as_float(__builtin_amdgcn_mov_dpp(__float_as_int(x), 0xB1, 0xF, 0xF, true));
    x += __int_as_float(__builtin_amdgcn_mov_dpp(__float_as_int(x), 0x4E, 0xF, 0xF, true));
    x += __int_as_float(__builtin_amdgcn_mov_dpp(__float_as_int(x), 0x141, 0xF, 0xF, true));
    return x;
}

// ------------------------------- rope tables -------------------------------
__global__ void rope_tables_k(float* __restrict__ cosT, float* __restrict__ sinT) {
    int idx = blockIdx.x * 256 + threadIdx.x;   // 32768 = 1024*32
    int l = idx >> 5, d = idx & 31;
    double ang = (double)l * pow(500000.0, -(double)(2 * d) / 64.0);
    cosT[idx] = (float)cos(ang);
    sinT[idx] = (float)sin(ang);
}

// ------------------------------- embedding ---------------------------------
__global__ void embed_k(const int* __restrict__ ids, const float* __restrict__ emb,
                        float* __restrict__ h) {
    int tok = blockIdx.x;
    int id = ids[tok];
    ((float4*)(h + (size_t)tok * HIDDEN))[threadIdx.x] =
        ((const float4*)(emb + (size_t)id * HIDDEN))[threadIdx.x];
}

// ------------------------------- casts -------------------------------------
__global__ void cast_plain(const float* __restrict__ s, bf16* __restrict__ d, int n4) {
    int i = blockIdx.x * 256 + threadIdx.x;
    if (i >= n4) return;
    float4 v = ((const float4*)s)[i];
    BF4 u;
    u.h[0] = (bf16)v.x; u.h[1] = (bf16)v.y; u.h[2] = (bf16)v.z; u.h[3] = (bf16)v.w;
    ((short4*)d)[i] = u.p;
}

// six 256x512 f32 matrices -> one fused 1536x512 bf16 (order s0..s5)
__global__ void cast6(const float* s0, const float* s1, const float* s2,
                      const float* s3, const float* s4, const float* s5,
                      bf16* __restrict__ d) {
    int i = blockIdx.x * 256 + threadIdx.x;      // 196608 short4s
    if (i >= 196608) return;
    int which = i >> 15, loc = i & 32767;
    const float* s = which == 0 ? s0 : which == 1 ? s1 : which == 2 ? s2
                    : which == 3 ? s3 : which == 4 ? s4 : s5;
    float4 v = ((const float4*)s)[loc];
    BF4 u;
    u.h[0] = (bf16)v.x; u.h[1] = (bf16)v.y; u.h[2] = (bf16)v.z; u.h[3] = (bf16)v.w;
    ((short4*)d)[i] = u.p;
}

// gather (layers,R,K) f32 -> fused bf16 rows [i*dstStride + dstOff + r*rowMul]
__global__ void cast_fuse(const float* __restrict__ s, bf16* __restrict__ d,
                          int R, int K4, int dstStride, int dstOff, int rowMul,
                          int total4) {
    int idx = blockIdx.x * 256 + threadIdx.x;
    if (idx >= total4) return;
    int perLayer = R * K4;
    int i = idx / perLayer;
    int rem = idx - i * perLayer;
    int r = rem / K4, c4 = rem - r * K4;
    float4 v = ((const float4*)s)[idx];
    BF4 u;
    u.h[0] = (bf16)v.x; u.h[1] = (bf16)v.y; u.h[2] = (bf16)v.z; u.h[3] = (bf16)v.w;
    ((short4*)d)[((size_t)i * dstStride + dstOff + r * rowMul) * K4 + c4] = u.p;
}

__global__ void cast_embed_pad(const float* __restrict__ s, bf16* __restrict__ d) {
    int i = blockIdx.x * 256 + threadIdx.x;   // 128*128 = 16384 short4s
    int row = i >> 7, c4 = i & 127;
    BF4 u;
    if (row < VOCN) {
        float4 v = ((const float4*)s)[row * 128 + c4];
        u.h[0] = (bf16)v.x; u.h[1] = (bf16)v.y; u.h[2] = (bf16)v.z; u.h[3] = (bf16)v.w;
    } else {
        u.h[0] = (bf16)0.f; u.h[1] = (bf16)0.f; u.h[2] = (bf16)0.f; u.h[3] = (bf16)0.f;
    }
    ((short4*)d)[i] = u.p;
}

// ------------------------------- rmsnorm -> bf16 ---------------------------
__global__ void rmsnorm512(const float* __restrict__ in, const float* __restrict__ w,
                           bf16* __restrict__ out) {
    int row = blockIdx.x, t = threadIdx.x;     // 128 threads
    float4 x = ((const float4*)(in + (size_t)row * 512))[t];
    float s = x.x * x.x + x.y * x.y + x.z * x.z + x.w * x.w;
    for (int m = 1; m < 64; m <<= 1) s += __shfl_xor(s, m);
    __shared__ float red[2];
    if ((t & 63) == 0) red[t >> 6] = s;
    __syncthreads();
    float tot = red[0] + red[1];
    float r = rsqrtf(tot * (1.f / 512.f) + 1e-6f);
    float4 wv = ((const float4*)w)[t];
    BF4 u;
    u.h[0] = (bf16)(x.x * r * wv.x); u.h[1] = (bf16)(x.y * r * wv.y);
    u.h[2] = (bf16)(x.z * r * wv.z); u.h[3] = (bf16)(x.w * r * wv.w);
    ((short4*)(out + (size_t)row * 512))[t] = u.p;
}

// ------------------------------- bf16 MFMA GEMM ----------------------------
// C = A(bf16, MxK rm) @ B(bf16, NxK rm)^T. 128x128 tile, Kstep 32, 4 waves.
// MODE 0: C(f32)=v  MODE 1: C(f32)+=v
// MODE 4: gate/up interleaved cols; Cb[row*Nreal+col/2]=bf16(silu(g)*u).
template <int MODE>
__global__ __launch_bounds__(256) void gemm_bf16(const bf16* __restrict__ A,
                                                 const bf16* __restrict__ B,
                                                 float* __restrict__ C,
                                                 bf16* __restrict__ Cb,
                                                 int M, int N, int K, int Nreal) {
    __shared__ bf16 As[128 * 32];
    __shared__ bf16 Bs[128 * 32];
    const int tid = threadIdx.x;
    const int wave = tid >> 6, lane = tid & 63;
    const int row0 = blockIdx.y * 128, col0 = blockIdx.x * 128;
    floatx4 acc[4][4];
#pragma unroll
    for (int i = 0; i < 4; ++i)
#pragma unroll
        for (int j = 0; j < 4; ++j) acc[i][j] = (floatx4){0.f, 0.f, 0.f, 0.f};
    const int m0 = (wave & 1) * 64, n0 = (wave >> 1) * 64;
    const int sr = tid >> 2;
    const int ske = (tid & 3) * 8;
    const size_t arow1 = (size_t)(row0 + sr) * K + ske;
    const size_t arow2 = (size_t)(row0 + 64 + sr) * K + ske;
    const size_t brow1 = (size_t)(col0 + sr) * K + ske;
    const size_t brow2 = (size_t)(col0 + 64 + sr) * K + ske;
    char* AsB = (char*)As;
    char* BsB = (char*)Bs;
    const int lds0 = wave * 1024, lds1 = 4096 + wave * 1024;

    for (int k0 = 0; k0 < K; k0 += 32) {
        gload16(A + arow1 + k0, AsB + lds0);
        gload16(A + arow2 + k0, AsB + lds1);
        gload16(B + brow1 + k0, BsB + lds0);
        gload16(B + brow2 + k0, BsB + lds1);
        __syncthreads();
        bf16x8 af[4], bfr[4];
#pragma unroll
        for (int mi = 0; mi < 4; ++mi)
            af[mi] = *(const bf16x8*)(AsB + ((m0 + mi * 16 + (lane & 15)) * 32 + (lane >> 4) * 8) * 2);
#pragma unroll
        for (int ni = 0; ni < 4; ++ni)
            bfr[ni] = *(const bf16x8*)(BsB + ((n0 + ni * 16 + (lane & 15)) * 32 + (lane >> 4) * 8) * 2);
#pragma unroll
        for (int mi = 0; mi < 4; ++mi)
#pragma unroll
            for (int ni = 0; ni < 4; ++ni)
                acc[mi][ni] = __builtin_amdgcn_mfma_f32_16x16x32_bf16(af[mi], bfr[ni], acc[mi][ni], 0, 0, 0);
        __syncthreads();
    }
    const int cr = (lane >> 4) * 4;
    const int cc = lane & 15;
#pragma unroll
    for (int mi = 0; mi < 4; ++mi) {
#pragma unroll
        for (int ni = 0; ni < 4; ++ni) {
#pragma unroll
            for (int r = 0; r < 4; ++r) {
                int row = row0 + m0 + mi * 16 + cr + r;
                int col = col0 + n0 + ni * 16 + cc;
                float v = acc[mi][ni][r];
                if (MODE == 4) {
                    float o = __shfl_xor(v, 1);
                    if (!(lane & 1)) {
                        float sg = v / (1.f + __expf(-v));
                        Cb[(size_t)row * Nreal + (col >> 1)] = (bf16)(sg * o);
                    }
                } else if (col < Nreal) {
                    size_t off = (size_t)row * Nreal + col;
                    if (MODE == 0) C[off] = v;
                    else if (MODE == 1) C[off] += v;
                }
            }
        }
    }
}

// ----------------- QKV prep: RoPE + bf16 cast + V transpose ----------------
__global__ void qkv_prep(const float* __restrict__ P, const float* __restrict__ cosT,
                         const float* __restrict__ sinT, bf16* __restrict__ Qb,
                         bf16* __restrict__ Kb, bf16* __restrict__ Vtb) {
    int tok = blockIdx.x;                       // 4096
    int b = tok >> 10, l = tok & 1023;
    int hh = threadIdx.x >> 5, d = threadIdx.x & 31;
    const float* q = P + (size_t)tok * 1536 + hh * 64;
    const float* k = q + 512;
    const float* v = q + 1024;
    float c = cosT[l * 32 + d], s = sinT[l * 32 + d];
    size_t base = ((size_t)(b * 8 + hh) * 1024 + l) * 64;
    float q1 = q[d], q2 = q[d + 32];
    Qb[base + d] = (bf16)(q1 * c - q2 * s);
    Qb[base + d + 32] = (bf16)(q2 * c + q1 * s);
    float k1 = k[d], k2 = k[d + 32];
    Kb[base + d] = (bf16)(k1 * c - k2 * s);
    Kb[base + d + 32] = (bf16)(k2 * c + k1 * s);
    size_t vb = (size_t)(b * 8 + hh) * 64 * 1024 + l;
    Vtb[vb + (size_t)d * 1024] = (bf16)v[d];
    Vtb[vb + (size_t)(d + 32) * 1024] = (bf16)v[d + 32];
}

// ------------------------- MFMA flash attention ----------------------------
__global__ __launch_bounds__(256) void attn_mfma(const bf16* __restrict__ Qb,
                                                 const bf16* __restrict__ Kb,
                                                 const bf16* __restrict__ Vtb,
                                                 bf16* __restrict__ O) {
    int qt = blockIdx.x, hh = blockIdx.y, b = blockIdx.z;
    int bh = b * 8 + hh;
    int q0 = qt * 64;
    const bf16* Qg = Qb + ((size_t)bh * 1024 + q0) * 64;
    const bf16* Kg = Kb + (size_t)bh * 1024 * 64;
    const bf16* Vg = Vtb + (size_t)bh * 64 * 1024;   // [64 d][1024 l]
    __shared__ bf16 Qs[64 * ATTS];
    __shared__ bf16 Ks[64 * ATTS];
    __shared__ bf16 Vs[64 * ATTS];
    __shared__ bf16 Ps[64 * ATTS];
    int tid = threadIdx.x, wave = tid >> 6, lane = tid & 63;
    int lr = lane & 15, quad = lane >> 4;

#pragma unroll
    for (int it = 0; it < 2; ++it) {
        int cidx = tid + it * 256;
        int row = cidx >> 3, ch = cidx & 7;
        *(bf16x8*)(Qs + row * ATTS + ch * 8) = *(const bf16x8*)(Qg + row * 64 + ch * 8);
    }
    float mrow[4], lrow[4];
    floatx4 Oacc[4];
#pragma unroll
    for (int r = 0; r < 4; ++r) { mrow[r] = -1e30f; lrow[r] = 0.f; }
#pragma unroll
    for (int d0 = 0; d0 < 4; ++d0) Oacc[d0] = (floatx4){0.f, 0.f, 0.f, 0.f};

    int ntiles = qt + 1;
    for (int t = 0; t < ntiles; ++t) {
        int kv0 = t * 64;
        __syncthreads();
#pragma unroll
        for (int it = 0; it < 2; ++it) {
            int cidx = tid + it * 256;
            int row = cidx >> 3, ch = cidx & 7;
            *(bf16x8*)(Ks + row * ATTS + ch * 8) =
                *(const bf16x8*)(Kg + (size_t)(kv0 + row) * 64 + ch * 8);
            *(bf16x8*)(Vs + row * ATTS + ch * 8) =
                *(const bf16x8*)(Vg + (size_t)row * 1024 + kv0 + ch * 8);
        }
        __syncthreads();
        bf16x8 aq[2];
#pragma unroll
        for (int kc = 0; kc < 2; ++kc)
            aq[kc] = *(const bf16x8*)(Qs + (wave * 16 + lr) * ATTS + kc * 32 + quad * 8);
        floatx4 sacc[4];
#pragma unroll
        for (int n0 = 0; n0 < 4; ++n0) {
            bf16x8 bk0 = *(const bf16x8*)(Ks + (n0 * 16 + lr) * ATTS + quad * 8);
            bf16x8 bk1 = *(const bf16x8*)(Ks + (n0 * 16 + lr) * ATTS + 32 + quad * 8);
            floatx4 z = (floatx4){0.f, 0.f, 0.f, 0.f};
            z = __builtin_amdgcn_mfma_f32_16x16x32_bf16(aq[0], bk0, z, 0, 0, 0);
            sacc[n0] = __builtin_amdgcn_mfma_f32_16x16x32_bf16(aq[1], bk1, z, 0, 0, 0);
        }
        float sv[4][4];
#pragma unroll
        for (int n0 = 0; n0 < 4; ++n0)
#pragma unroll
            for (int r = 0; r < 4; ++r) sv[n0][r] = sacc[n0][r] * 0.125f;
        if (t == ntiles - 1) {
#pragma unroll
            for (int n0 = 0; n0 < 4; ++n0)
#pragma unroll
                for (int r = 0; r < 4; ++r)
                    if (n0 * 16 + lr > wave * 16 + quad * 4 + r) sv[n0][r] = -1e30f;
        }
        float al[4];
#pragma unroll
        for (int r = 0; r < 4; ++r) {
            float tm = fmaxf(fmaxf(sv[0][r], sv[1][r]), fmaxf(sv[2][r], sv[3][r]));
            tm = fmaxf(tm, __shfl_xor(tm, 1));
            tm = fmaxf(tm, __shfl_xor(tm, 2));
            tm = fmaxf(tm, __shfl_xor(tm, 4));
            tm = fmaxf(tm, __shfl_xor(tm, 8));
            float mn = fmaxf(mrow[r], tm);
            al[r] = __expf(mrow[r] - mn);
            mrow[r] = mn;
        }
        float rs[4];
#pragma unroll
        for (int r = 0; r < 4; ++r) rs[r] = 0.f;
#pragma unroll
        for (int n0 = 0; n0 < 4; ++n0)
#pragma unroll
            for (int r = 0; r < 4; ++r) {
                float p = __expf(sv[n0][r] - mrow[r]);
                sv[n0][r] = p;
                rs[r] += p;
            }
#pragma unroll
        for (int r = 0; r < 4; ++r) {
            float t2 = rs[r];
            t2 += __shfl_xor(t2, 1);
            t2 += __shfl_xor(t2, 2);
            t2 += __shfl_xor(t2, 4);
            t2 += __shfl_xor(t2, 8);
            lrow[r] = lrow[r] * al[r] + t2;
        }
#pragma unroll
        for (int d0 = 0; d0 < 4; ++d0)
#pragma unroll
            for (int r = 0; r < 4; ++r) Oacc[d0][r] *= al[r];
#pragma unroll
        for (int n0 = 0; n0 < 4; ++n0)
#pragma unroll
            for (int r = 0; r < 4; ++r)
                Ps[(wave * 16 + quad * 4 + r) * ATTS + n0 * 16 + lr] = (bf16)sv[n0][r];
        bf16x8 ap[2];
#pragma unroll
        for (int kc = 0; kc < 2; ++kc)
            ap[kc] = *(const bf16x8*)(Ps + (wave * 16 + lr) * ATTS + kc * 32 + quad * 8);
#pragma unroll
        for (int d0 = 0; d0 < 4; ++d0) {
            bf16x8 bv0 = *(const bf16x8*)(Vs + (d0 * 16 + lr) * ATTS + quad * 8);
            bf16x8 bv1 = *(const bf16x8*)(Vs + (d0 * 16 + lr) * ATTS + 32 + quad * 8);
            Oacc[d0] = __builtin_amdgcn_mfma_f32_16x16x32_bf16(ap[0], bv0, Oacc[d0], 0, 0, 0);
            Oacc[d0] = __builtin_amdgcn_mfma_f32_16x16x32_bf16(ap[1], bv1, Oacc[d0], 0, 0, 0);
        }
    }
    float inv[4];
#pragma unroll
    for (int r = 0; r < 4; ++r) inv[r] = 1.f / lrow[r];
#pragma unroll
    for (int d0 = 0; d0 < 4; ++d0)
#pragma unroll
        for (int r = 0; r < 4; ++r) {
            int row = b * 1024 + q0 + wave * 16 + quad * 4 + r;
            int col = hh * 64 + d0 * 16 + lr;
            O[(size_t)row * 512 + col] = (bf16)(Oacc[d0][r] * inv[r]);
        }
}

// ------------------------------- delta scan --------------------------------
// 32 blocks (one per b,h) x 4 waves. Wave w owns S rows w*8..w*8+7; lane =
// (row ri = wave*8 + (lane>>3), col group c = lane&7, 4 S elems). Rows are
// independent given shared k_t/q_t -> no intra-chunk syncs; 8-lane dot
// reductions via DPP sum8 (VALU pipe). ctx staged in LDS, flushed per chunk.
// Descaled state S_real = D*S, branchless rescale every 16 steps.
__global__ __launch_bounds__(256, 1) void delta_scan(
    const float* __restrict__ P, const float* __restrict__ S_in,
    const float* __restrict__ bbias, const float* __restrict__ abias,
    float* __restrict__ S_out, float* __restrict__ ctx) {
    int bh = blockIdx.x;
    int b = bh >> 3, hh = bh & 7;
    int tid = threadIdx.x;
    int lane = tid & 63, wave = tid >> 6;
    int ri = wave * 8 + (lane >> 3);
    int c = lane & 7;
    bool cz = (c == 0);
    __shared__ __align__(16) float ks[66][36], qs[66][36], vs[66][36],
                                   bs[66][36], as_[66][36];
    __shared__ __align__(16) float cs[64][32];
    float4 S = *(const float4*)(S_in + ((size_t)bh * 32 + ri) * 32 + c * 4);

    int sc4 = tid & 7, sr0 = tid >> 3;   // staging: token rows sr0, sr0+32
    float4 bB = *(const float4*)(bbias + hh * 32 + sc4 * 4);
    float4 bA = *(const float4*)(abias + hh * 32 + sc4 * 4);
    float D = 1.f, Dinv = 1.f;

    float4 ka, qa, kb, qb;
    float aa, ba, va, a2, b2, v2;

    auto loadt = [&](int t, float4& k4, float4& q4, float& ax, float& bx, float& vx) {
        k4 = *(const float4*)&ks[t][c * 4];
        q4 = *(const float4*)&qs[t][c * 4];
        ax = as_[t][ri]; bx = bs[t][ri]; vx = vs[t][ri];
    };
    auto stepf = [&](float4 k4, float4 q4, float ax, float bx, float vx, int t) {
        float d = fmaf(S.w, k4.w, fmaf(S.z, k4.z, fmaf(S.y, k4.y, S.x * k4.x)));
        float dot = sum8(d);
        float u = bx * (vx - ax * (D * dot));
        D *= ax;
        Dinv *= __builtin_amdgcn_rcpf(ax);
        float ud = u * Dinv;
        S.x = fmaf(ud, k4.x, S.x);
        S.y = fmaf(ud, k4.y, S.y);
        S.z = fmaf(ud, k4.z, S.z);
        S.w = fmaf(ud, k4.w, S.w);
        float e = fmaf(S.w, q4.w, fmaf(S.z, q4.z, fmaf(S.y, q4.y, S.x * q4.x)));
        float rd = sum8(e);
        if (cz) cs[t][ri] = D * rd;
    };

    for (int c0 = 0; c0 < LSEQ; c0 += 64) {
        __syncthreads();
        const float* Pb = P + ((size_t)(b * 1024 + c0) * 1536) + hh * 32 + sc4 * 4;
#pragma unroll
        for (int it = 0; it < 2; ++it) {
            int tok = sr0 + it * 32;
            const float* pg = Pb + (size_t)tok * 1536;
            float4 kv = *(const float4*)(pg);
            float4 vv = *(const float4*)(pg + 256);
            float4 qv = *(const float4*)(pg + 512);
            float4 bv = *(const float4*)(pg + 768);
            float4 av = *(const float4*)(pg + 1024);
            float ss = kv.x * kv.x + kv.y * kv.y + kv.z * kv.z + kv.w * kv.w;
            ss = sum8(ss);
            float rn = 1.f / fmaxf(sqrtf(ss), 1e-12f);
            kv.x *= rn; kv.y *= rn; kv.z *= rn; kv.w *= rn;
            *(float4*)&ks[tok][sc4 * 4] = kv;
            *(float4*)&vs[tok][sc4 * 4] = vv;
            *(float4*)&qs[tok][sc4 * 4] = qv;
            float4 bo, ao;
            bo.x = 1.f / (1.f + __expf(-(bv.x + bB.x)));
            bo.y = 1.f / (1.f + __expf(-(bv.y + bB.y)));
            bo.z = 1.f / (1.f + __expf(-(bv.z + bB.z)));
            bo.w = 1.f / (1.f + __expf(-(bv.w + bB.w)));
            ao.x = 1.f / (1.f + __expf(-(av.x + bA.x)));
            ao.y = 1.f / (1.f + __expf(-(av.y + bA.y)));
            ao.z = 1.f / (1.f + __expf(-(av.z + bA.z)));
            ao.w = 1.f / (1.f + __expf(-(av.w + bA.w)));
            *(float4*)&bs[tok][sc4 * 4] = bo;
            *(float4*)&as_[tok][sc4 * 4] = ao;
        }
        __syncthreads();
#pragma unroll
        for (int sb = 0; sb < 4; ++sb) {
            int t0 = sb * 16;
            loadt(t0, ka, qa, aa, ba, va);
            for (int t = 0; t < 16; t += 2) {
                loadt(t0 + t + 1, kb, qb, a2, b2, v2);
                stepf(ka, qa, aa, ba, va, t0 + t);
                loadt(t0 + t + 2, ka, qa, aa, ba, va);   // t==64 pad row: unused
                stepf(kb, qb, a2, b2, v2, t0 + t + 1);
            }
            S.x *= D; S.y *= D; S.z *= D; S.w *= D;
            D = 1.f; Dinv = 1.f;
        }
        __syncthreads();
        // coalesced ctx flush for this chunk
        int gbase = b * 1024 + c0;
        for (int e = tid; e < 512; e += 256) {
            int t = e >> 3, j4 = e & 7;
            float4 val = *(const float4*)&cs[t][j4 * 4];
            *(float4*)(ctx + (size_t)(gbase + t) * 256 + hh * 32 + j4 * 4) = val;
        }
    }
    *(float4*)(S_out + ((size_t)bh * 32 + ri) * 32 + c * 4) = S;
}

// ------------- ctxbf = bf16(rmsnorm(ctx,nw)*silu(gate)), gate in P@1280 ----
__global__ void ctx_post(const float* __restrict__ ctx, const float* __restrict__ P,
                         const float* __restrict__ nw, bf16* __restrict__ out) {
    int row = blockIdx.x, t = threadIdx.x;  // 64 threads
    float4 x = ((const float4*)(ctx + (size_t)row * SDIMM))[t];
    float s = x.x * x.x + x.y * x.y + x.z * x.z + x.w * x.w;
    for (int m = 1; m < 64; m <<= 1) s += __shfl_xor(s, m);
    float r = rsqrtf(s * (1.f / 256.f) + 1e-6f);
    float4 n = ((const float4*)nw)[t];
    float4 g = ((const float4*)(P + (size_t)row * 1536 + 1280))[t];
    BF4 u;
    u.h[0] = (bf16)(x.x * r * n.x * (g.x / (1.f + __expf(-g.x))));
    u.h[1] = (bf16)(x.y * r * n.y * (g.y / (1.f + __expf(-g.y))));
    u.h[2] = (bf16)(x.z * r * n.z * (g.z / (1.f + __expf(-g.z))));
    u.h[3] = (bf16)(x.w * r * n.w * (g.w / (1.f + __expf(-g.w))));
    ((short4*)(out + (size_t)row * SDIMM))[t] = u.p;
}

// ---------------------------------------------------------------------------
extern "C" void kernel_launch(void* const* d_in, const int* in_sizes, int n_in,
                              void* d_out, int out_size, void* d_ws, size_t ws_size,
                              hipStream_t stream) {
    (void)in_sizes; (void)n_in; (void)out_size; (void)ws_size;
    const int* ids = (const int*)d_in[0];
    const float* state = (const float*)d_in[1];
    const float* embedw = (const float*)d_in[2];
    auto F = [&](int i) { return (const float*)d_in[i]; };

    char* wsb = (char*)d_ws;
    const size_t MB = 1048576;
    float* H    = (float*)(wsb);                 // 0-8 MB
    bf16*  XNbf = (bf16*)(wsb + 8 * MB);         // 8-12 (alias ctxf in delta)
    float* ctxf = (float*)(wsb + 8 * MB);
    bf16*  Hbf  = (bf16*)(wsb + 12 * MB);        // 12-16 (alias ctxb)
    bf16*  ctxb = (bf16*)(wsb + 12 * MB);
    float* P    = (float*)(wsb + 16 * MB);       // 16-40 (QKV f32 / delta f32)
    bf16*  Obf  = (bf16*)(wsb + 40 * MB);        // 40-44 attn out
    bf16*  Qbuf = (bf16*)(wsb + 44 * MB);        // 44-48
    bf16*  Kbuf = (bf16*)(wsb + 48 * MB);        // 48-52
    bf16*  Vtb  = (bf16*)(wsb + 52 * MB);        // 52-56
    bf16*  A1b  = (bf16*)(wsb + 44 * MB);        // alias Q/K/Vt (dead after attn)
    float* cosT = (float*)(wsb + 58 * MB);
    float* sinT = cosT + 32768;
    float* Sbuf = sinT + 32768;
    char*  wbase = wsb + 59 * MB;
    bf16* wqkv  = (bf16*)(wbase);                        // 6x1536x512
    bf16* wob   = (bf16*)(wbase + 9437184);              // 6x512x512
    bf16* wgu   = (bf16*)(wbase + 12582912);             // 6x3072x512 interleaved
    bf16* wdnb  = (bf16*)(wbase + 31457280);             // 6x512x1536
    bf16* wdR   = (bf16*)(wbase + 40894464);             // 1536x512
    bf16* woutR = (bf16*)(wbase + 42467328);             // 512x256
    bf16* wdW   = (bf16*)(wbase + 42729472);             // 1536x512
    bf16* woutW = (bf16*)(wbase + 44302336);             // 512x256
    bf16* embp  = (bf16*)(wbase + 44564480);             // 128x512 padded

    float* out = (float*)d_out;
    float* logits = out;
    float* Sout = out + 4096 * VOCN;

    auto G = [&](int mode, const bf16* A, const bf16* B, float* C, bf16* Cb,
                 int M, int N, int K, int Nreal) {
        dim3 grid(N / 128, M / 128);
        if (mode == 0) gemm_bf16<0><<<grid, 256, 0, stream>>>(A, B, C, Cb, M, N, K, Nreal);
        else if (mode == 1) gemm_bf16<1><<<grid, 256, 0, stream>>>(A, B, C, Cb, M, N, K, Nreal);
        else gemm_bf16<4><<<grid, 256, 0, stream>>>(A, B, C, Cb, M, N, K, Nreal);
    };
    auto CP = [&](const float* s, bf16* d, int n4) {
        cast_plain<<<(n4 + 255) / 256, 256, 0, stream>>>(s, d, n4);
    };

    // ---- weight casts ----
    cast_fuse<<<1536, 256, 0, stream>>>(F(24), wqkv, 512, 128, 1536, 0, 1, 393216);
    cast_fuse<<<1536, 256, 0, stream>>>(F(25), wqkv, 512, 128, 1536, 512, 1, 393216);
    cast_fuse<<<1536, 256, 0, stream>>>(F(26), wqkv, 512, 128, 1536, 1024, 1, 393216);
    CP(F(27), wob, 393216);
    cast_fuse<<<4608, 256, 0, stream>>>(F(29), wgu, 1536, 128, 3072, 0, 2, 1179648);
    cast_fuse<<<4608, 256, 0, stream>>>(F(30), wgu, 1536, 128, 3072, 1, 2, 1179648);
    CP(F(31), wdnb, 1179648);
    cast6<<<768, 256, 0, stream>>>(F(3), F(4), F(5), F(6), F(8), F(12), wdR);
    CP(F(10), woutR, 32768);
    cast6<<<768, 256, 0, stream>>>(F(13), F(14), F(15), F(16), F(18), F(22), wdW);
    CP(F(20), woutW, 32768);
    cast_embed_pad<<<64, 256, 0, stream>>>(embedw, embp);

    rope_tables_k<<<128, 256, 0, stream>>>(cosT, sinT);
    embed_k<<<4096, 128, 0, stream>>>(ids, embedw, H);

    // ---- delta read ----
    CP(H, Hbf, 524288);
    G(0, Hbf, wdR, P, nullptr, 4096, 1536, 512, 1536);
    delta_scan<<<32, 256, 0, stream>>>(P, state, F(7), F(9), Sbuf, ctxf);
    ctx_post<<<4096, 64, 0, stream>>>(ctxf, P, F(11), ctxb);
    G(1, ctxb, woutR, H, nullptr, 4096, 512, 256, 512);

    for (int i = 0; i < 6; ++i) {
        rmsnorm512<<<4096, 128, 0, stream>>>(H, F(23) + (size_t)i * 512, XNbf);
        G(0, XNbf, wqkv + (size_t)i * 1536 * 512, P, nullptr, 4096, 1536, 512, 1536);
        qkv_prep<<<4096, 256, 0, stream>>>(P, cosT, sinT, Qbuf, Kbuf, Vtb);
        attn_mfma<<<dim3(16, 8, 4), 256, 0, stream>>>(Qbuf, Kbuf, Vtb, Obf);
        G(1, Obf, wob + (size_t)i * 512 * 512, H, nullptr, 4096, 512, 512, 512);
        rmsnorm512<<<4096, 128, 0, stream>>>(H, F(28) + (size_t)i * 512, XNbf);
        G(4, XNbf, wgu + (size_t)i * 3072 * 512, nullptr, A1b, 4096, 3072, 512, 1536);
        G(1, A1b, wdnb + (size_t)i * 512 * 1536, H, nullptr, 4096, 512, 1536, 512);
    }

    // ---- delta write ----
    CP(H, Hbf, 524288);
    G(0, Hbf, wdW, P, nullptr, 4096, 1536, 512, 1536);
    delta_scan<<<32, 256, 0, stream>>>(P, Sbuf, F(17), F(19), Sout, ctxf);
    ctx_post<<<4096, 64, 0, stream>>>(ctxf, P, F(21), ctxb);
    G(1, ctxb, woutW, H, nullptr, 4096, 512, 256, 512);

    rmsnorm512<<<4096, 128, 0, stream>>>(H, F(32), XNbf);
    G(0, XNbf, embp, logits, nullptr, 4096, 128, 512, VOCN);
}

// Round 8
// 1459.642 us; speedup vs baseline: 1.7058x; 1.1516x over previous
//
#include <hip/hip_runtime.h>
#include <hip/hip_bf16.h>
#include <math.h>

// ---------------------------------------------------------------------------
// BashTransformer forward on MI355X. Round 8: RoPE+cast+V-transpose fused
// into QKV GEMM epilogue (MODE 5), 64x128-tile GEMM for N=512 accumulate
// GEMMs (2x grid fill), merged weight casts. Scan/attn cores from round 7.
// ---------------------------------------------------------------------------

#define LSEQ 1024
#define BATCH 4
#define HIDDEN 512
#define NHEAD 8
#define HDIM 64
#define SHEAD 8
#define SDHD 32
#define SDIMM 256
#define FFND 1536
#define VOCN 63
#define ATTS 72   // attn LDS row stride (elems): 144B = 16B-aligned, 2-way banks

typedef __bf16 bf16;
typedef __attribute__((ext_vector_type(8))) __bf16 bf16x8;
typedef __attribute__((ext_vector_type(4))) float floatx4;

union BF4 { bf16 h[4]; short4 p; };

__device__ __forceinline__ void gload16(const void* g, const void* l) {
    __builtin_amdgcn_global_load_lds(
        (__attribute__((address_space(1))) unsigned int*)(uintptr_t)g,
        (__attribute__((address_space(3))) unsigned int*)(unsigned int)(uintptr_t)l,
        16, 0, 0);
}

// sum over aligned groups of 8 lanes, pure DPP (VALU pipe, no LDS counters)
__device__ __forceinline__ float sum8(float x) {
    x += __int_as_float(__builtin_amdgcn_mov_dpp(__float_as_int(x), 0xB1, 0xF, 0xF, true));
    x += __int_as_float(__builtin_amdgcn_mov_dpp(__float_as_int(x), 0x4E, 0xF, 0xF, true));
    x += __int_as_float(__builtin_amdgcn_mov_dpp(__float_as_int(x), 0x141, 0xF, 0xF, true));
    return x;
}

// ------------------------------- rope tables -------------------------------
__global__ void rope_tables_k(float* __restrict__ cosT, float* __restrict__ sinT) {
    int idx = blockIdx.x * 256 + threadIdx.x;   // 32768 = 1024*32
    int l = idx >> 5, d = idx & 31;
    double ang = (double)l * pow(500000.0, -(double)(2 * d) / 64.0);
    cosT[idx] = (float)cos(ang);
    sinT[idx] = (float)sin(ang);
}

// ------------------------------- embedding ---------------------------------
__global__ void embed_k(const int* __restrict__ ids, const float* __restrict__ emb,
                        float* __restrict__ h) {
    int tok = blockIdx.x;
    int id = ids[tok];
    ((float4*)(h + (size_t)tok * HIDDEN))[threadIdx.x] =
        ((const float4*)(emb + (size_t)id * HIDDEN))[threadIdx.x];
}

// ------------------------------- casts -------------------------------------
__global__ void cast_plain(const float* __restrict__ s, bf16* __restrict__ d, int n4) {
    int i = blockIdx.x * 256 + threadIdx.x;
    if (i >= n4) return;
    float4 v = ((const float4*)s)[i];
    BF4 u;
    u.h[0] = (bf16)v.x; u.h[1] = (bf16)v.y; u.h[2] = (bf16)v.z; u.h[3] = (bf16)v.w;
    ((short4*)d)[i] = u.p;
}

// six 256x512 f32 matrices -> one fused 1536x512 bf16 (order s0..s5)
__global__ void cast6(const float* s0, const float* s1, const float* s2,
                      const float* s3, const float* s4, const float* s5,
                      bf16* __restrict__ d) {
    int i = blockIdx.x * 256 + threadIdx.x;      // 196608 short4s
    if (i >= 196608) return;
    int which = i >> 15, loc = i & 32767;
    const float* s = which == 0 ? s0 : which == 1 ? s1 : which == 2 ? s2
                    : which == 3 ? s3 : which == 4 ? s4 : s5;
    float4 v = ((const float4*)s)[loc];
    BF4 u;
    u.h[0] = (bf16)v.x; u.h[1] = (bf16)v.y; u.h[2] = (bf16)v.z; u.h[3] = (bf16)v.w;
    ((short4*)d)[i] = u.p;
}

// wq/wk/wv (6,512,512) each -> fused (6,1536,512) rows [layer*1536+which*512+r]
__global__ void cast_qkv(const float* __restrict__ q, const float* __restrict__ k,
                         const float* __restrict__ v, bf16* __restrict__ d) {
    int idx = blockIdx.x * 256 + threadIdx.x;    // 3*393216
    if (idx >= 1179648) return;
    int which = idx / 393216;
    int rem = idx - which * 393216;
    const float* s = which == 0 ? q : which == 1 ? k : v;
    int layer = rem >> 16, rr = rem & 65535;     // 512*128 per layer
    int r = rr >> 7, c4 = rr & 127;
    float4 x = ((const float4*)s)[rem];
    BF4 u;
    u.h[0] = (bf16)x.x; u.h[1] = (bf16)x.y; u.h[2] = (bf16)x.z; u.h[3] = (bf16)x.w;
    ((short4*)d)[((size_t)layer * 1536 + which * 512 + r) * 128 + c4] = u.p;
}

// w_gate/w_up (6,1536,512) -> interleaved (6,3072,512) rows [layer*3072+2r+which]
__global__ void cast_gu(const float* __restrict__ g, const float* __restrict__ uu,
                        bf16* __restrict__ d) {
    int idx = blockIdx.x * 256 + threadIdx.x;    // 2*1179648
    if (idx >= 2359296) return;
    int which = idx / 1179648;
    int rem = idx - which * 1179648;
    const float* s = which == 0 ? g : uu;
    int layer = rem / 196608, rr = rem - layer * 196608;  // 1536*128
    int r = rr >> 7, c4 = rr & 127;
    float4 x = ((const float4*)s)[rem];
    BF4 u;
    u.h[0] = (bf16)x.x; u.h[1] = (bf16)x.y; u.h[2] = (bf16)x.z; u.h[3] = (bf16)x.w;
    ((short4*)d)[((size_t)layer * 3072 + r * 2 + which) * 128 + c4] = u.p;
}

__global__ void cast_embed_pad(const float* __restrict__ s, bf16* __restrict__ d) {
    int i = blockIdx.x * 256 + threadIdx.x;   // 128*128 = 16384 short4s
    int row = i >> 7, c4 = i & 127;
    BF4 u;
    if (row < VOCN) {
        float4 v = ((const float4*)s)[row * 128 + c4];
        u.h[0] = (bf16)v.x; u.h[1] = (bf16)v.y; u.h[2] = (bf16)v.z; u.h[3] = (bf16)v.w;
    } else {
        u.h[0] = (bf16)0.f; u.h[1] = (bf16)0.f; u.h[2] = (bf16)0.f; u.h[3] = (bf16)0.f;
    }
    ((short4*)d)[i] = u.p;
}

// ------------------------------- rmsnorm -> bf16 ---------------------------
__global__ void rmsnorm512(const float* __restrict__ in, const float* __restrict__ w,
                           bf16* __restrict__ out) {
    int row = blockIdx.x, t = threadIdx.x;     // 128 threads
    float4 x = ((const float4*)(in + (size_t)row * 512))[t];
    float s = x.x * x.x + x.y * x.y + x.z * x.z + x.w * x.w;
    for (int m = 1; m < 64; m <<= 1) s += __shfl_xor(s, m);
    __shared__ float red[2];
    if ((t & 63) == 0) red[t >> 6] = s;
    __syncthreads();
    float tot = red[0] + red[1];
    float r = rsqrtf(tot * (1.f / 512.f) + 1e-6f);
    float4 wv = ((const float4*)w)[t];
    BF4 u;
    u.h[0] = (bf16)(x.x * r * wv.x); u.h[1] = (bf16)(x.y * r * wv.y);
    u.h[2] = (bf16)(x.z * r * wv.z); u.h[3] = (bf16)(x.w * r * wv.w);
    ((short4*)(out + (size_t)row * 512))[t] = u.p;
}

// ------------------------------- bf16 MFMA GEMM (128x128) ------------------
// C = A(bf16, MxK rm) @ B(bf16, NxK rm)^T. 128x128 tile, Kstep 32, 4 waves.
// MODE 0: C(f32)=v
// MODE 4: gate/up interleaved cols; Cb[row*Nreal+col/2]=bf16(silu(g)*u)
// MODE 5: fused QKV epilogue: RoPE(q,k)->Qb/Kb bf16 [bh][l][64], v->Vtb
//         [bh][d][l]. Requires N=1536 layout q|k|v and M = b-major tokens.
template <int MODE>
__global__ __launch_bounds__(256) void gemm_bf16(const bf16* __restrict__ A,
                                                 const bf16* __restrict__ B,
                                                 float* __restrict__ C,
                                                 bf16* __restrict__ Cb,
                                                 const float* __restrict__ cosT,
                                                 const float* __restrict__ sinT,
                                                 bf16* __restrict__ Qb,
                                                 bf16* __restrict__ Kb,
                                                 bf16* __restrict__ Vtb,
                                                 int M, int N, int K, int Nreal) {
    __shared__ bf16 As[128 * 32];
    __shared__ bf16 Bs[128 * 32];
    const int tid = threadIdx.x;
    const int wave = tid >> 6, lane = tid & 63;
    const int row0 = blockIdx.y * 128, col0 = blockIdx.x * 128;
    floatx4 acc[4][4];
#pragma unroll
    for (int i = 0; i < 4; ++i)
#pragma unroll
        for (int j = 0; j < 4; ++j) acc[i][j] = (floatx4){0.f, 0.f, 0.f, 0.f};
    const int m0 = (wave & 1) * 64, n0 = (wave >> 1) * 64;
    const int sr = tid >> 2;
    const int ske = (tid & 3) * 8;
    const size_t arow1 = (size_t)(row0 + sr) * K + ske;
    const size_t arow2 = (size_t)(row0 + 64 + sr) * K + ske;
    const size_t brow1 = (size_t)(col0 + sr) * K + ske;
    const size_t brow2 = (size_t)(col0 + 64 + sr) * K + ske;
    char* AsB = (char*)As;
    char* BsB = (char*)Bs;
    const int lds0 = wave * 1024, lds1 = 4096 + wave * 1024;

    for (int k0 = 0; k0 < K; k0 += 32) {
        gload16(A + arow1 + k0, AsB + lds0);
        gload16(A + arow2 + k0, AsB + lds1);
        gload16(B + brow1 + k0, BsB + lds0);
        gload16(B + brow2 + k0, BsB + lds1);
        __syncthreads();
        bf16x8 af[4], bfr[4];
#pragma unroll
        for (int mi = 0; mi < 4; ++mi)
            af[mi] = *(const bf16x8*)(AsB + ((m0 + mi * 16 + (lane & 15)) * 32 + (lane >> 4) * 8) * 2);
#pragma unroll
        for (int ni = 0; ni < 4; ++ni)
            bfr[ni] = *(const bf16x8*)(BsB + ((n0 + ni * 16 + (lane & 15)) * 32 + (lane >> 4) * 8) * 2);
#pragma unroll
        for (int mi = 0; mi < 4; ++mi)
#pragma unroll
            for (int ni = 0; ni < 4; ++ni)
                acc[mi][ni] = __builtin_amdgcn_mfma_f32_16x16x32_bf16(af[mi], bfr[ni], acc[mi][ni], 0, 0, 0);
        __syncthreads();
    }
    const int cr = (lane >> 4) * 4;
    const int cc = lane & 15;
    if (MODE == 5) {
        // wave-uniform 64-col span: segment + head fixed per wave
        int segbase = col0 + n0;
        int seg = segbase >> 9;           // 0=q 1=k 2=v
        int head = (segbase >> 6) & 7;
#pragma unroll
        for (int mi = 0; mi < 4; ++mi) {
#pragma unroll
            for (int r = 0; r < 4; ++r) {
                int row = row0 + m0 + mi * 16 + cr + r;
                int b = row >> 10, l = row & 1023;
                size_t bh = (size_t)(b * 8 + head);
                float x0 = acc[mi][0][r], x1 = acc[mi][1][r];
                float x2 = acc[mi][2][r], x3 = acc[mi][3][r];
                if (seg < 2) {
                    float c0 = cosT[l * 32 + cc], c1 = cosT[l * 32 + 16 + cc];
                    float s0 = sinT[l * 32 + cc], s1 = sinT[l * 32 + 16 + cc];
                    bf16* dst = (seg == 0 ? Qb : Kb) + bh * 65536 + l * 64;
                    dst[cc]      = (bf16)(x0 * c0 - x2 * s0);
                    dst[16 + cc] = (bf16)(x1 * c1 - x3 * s1);
                    dst[32 + cc] = (bf16)(x2 * c0 + x0 * s0);
                    dst[48 + cc] = (bf16)(x3 * c1 + x1 * s1);
                } else {
                    bf16* dst = Vtb + bh * 65536 + l;
                    dst[(size_t)(cc) * 1024]      = (bf16)x0;
                    dst[(size_t)(16 + cc) * 1024] = (bf16)x1;
                    dst[(size_t)(32 + cc) * 1024] = (bf16)x2;
                    dst[(size_t)(48 + cc) * 1024] = (bf16)x3;
                }
            }
        }
        return;
    }
#pragma unroll
    for (int mi = 0; mi < 4; ++mi) {
#pragma unroll
        for (int ni = 0; ni < 4; ++ni) {
#pragma unroll
            for (int r = 0; r < 4; ++r) {
                int row = row0 + m0 + mi * 16 + cr + r;
                int col = col0 + n0 + ni * 16 + cc;
                float v = acc[mi][ni][r];
                if (MODE == 4) {
                    float o = __shfl_xor(v, 1);
                    if (!(lane & 1)) {
                        float sg = v / (1.f + __expf(-v));
                        Cb[(size_t)row * Nreal + (col >> 1)] = (bf16)(sg * o);
                    }
                } else if (col < Nreal) {
                    size_t off = (size_t)row * Nreal + col;
                    if (MODE == 0) C[off] = v;
                }
            }
        }
    }
}

// ---------------------- 64x128-tile GEMM (accumulate) ----------------------
// Tile M=64, N=128, 4 waves each 32x64. Doubles grid fill for N=512 GEMMs.
// MODE 0: C=v  MODE 1: C+=v
template <int MODE>
__global__ __launch_bounds__(256) void gemm64_bf16(const bf16* __restrict__ A,
                                                   const bf16* __restrict__ B,
                                                   float* __restrict__ C,
                                                   int M, int N, int K, int Nreal) {
    __shared__ bf16 As[64 * 32];
    __shared__ bf16 Bs[128 * 32];
    const int tid = threadIdx.x;
    const int wave = tid >> 6, lane = tid & 63;
    const int row0 = blockIdx.y * 64, col0 = blockIdx.x * 128;
    floatx4 acc[2][4];
#pragma unroll
    for (int i = 0; i < 2; ++i)
#pragma unroll
        for (int j = 0; j < 4; ++j) acc[i][j] = (floatx4){0.f, 0.f, 0.f, 0.f};
    const int m0 = (wave & 1) * 32, n0 = (wave >> 1) * 64;
    const int sr = tid >> 2;
    const int ske = (tid & 3) * 8;
    const size_t arow = (size_t)(row0 + sr) * K + ske;
    const size_t brow1 = (size_t)(col0 + sr) * K + ske;
    const size_t brow2 = (size_t)(col0 + 64 + sr) * K + ske;
    char* AsB = (char*)As;
    char* BsB = (char*)Bs;
    const int lds0 = wave * 1024, lds1 = 4096 + wave * 1024;

    for (int k0 = 0; k0 < K; k0 += 32) {
        gload16(A + arow + k0, AsB + tid * 16);
        gload16(B + brow1 + k0, BsB + lds0);
        gload16(B + brow2 + k0, BsB + lds1);
        __syncthreads();
        bf16x8 af[2], bfr[4];
#pragma unroll
        for (int mi = 0; mi < 2; ++mi)
            af[mi] = *(const bf16x8*)(AsB + ((m0 + mi * 16 + (lane & 15)) * 32 + (lane >> 4) * 8) * 2);
#pragma unroll
        for (int ni = 0; ni < 4; ++ni)
            bfr[ni] = *(const bf16x8*)(BsB + ((n0 + ni * 16 + (lane & 15)) * 32 + (lane >> 4) * 8) * 2);
#pragma unroll
        for (int mi = 0; mi < 2; ++mi)
#pragma unroll
            for (int ni = 0; ni < 4; ++ni)
                acc[mi][ni] = __builtin_amdgcn_mfma_f32_16x16x32_bf16(af[mi], bfr[ni], acc[mi][ni], 0, 0, 0);
        __syncthreads();
    }
    const int cr = (lane >> 4) * 4;
    const int cc = lane & 15;
#pragma unroll
    for (int mi = 0; mi < 2; ++mi) {
#pragma unroll
        for (int ni = 0; ni < 4; ++ni) {
#pragma unroll
            for (int r = 0; r < 4; ++r) {
                int row = row0 + m0 + mi * 16 + cr + r;
                int col = col0 + n0 + ni * 16 + cc;
                if (col < Nreal) {
                    size_t off = (size_t)row * Nreal + col;
                    float v = acc[mi][ni][r];
                    if (MODE == 0) C[off] = v;
                    else C[off] += v;
                }
            }
        }
    }
}

// ------------------------- MFMA flash attention ----------------------------
__global__ __launch_bounds__(256) void attn_mfma(const bf16* __restrict__ Qb,
                                                 const bf16* __restrict__ Kb,
                                                 const bf16* __restrict__ Vtb,
                                                 bf16* __restrict__ O) {
    int qt = blockIdx.x, hh = blockIdx.y, b = blockIdx.z;
    int bh = b * 8 + hh;
    int q0 = qt * 64;
    const bf16* Qg = Qb + ((size_t)bh * 1024 + q0) * 64;
    const bf16* Kg = Kb + (size_t)bh * 1024 * 64;
    const bf16* Vg = Vtb + (size_t)bh * 64 * 1024;   // [64 d][1024 l]
    __shared__ bf16 Qs[64 * ATTS];
    __shared__ bf16 Ks[64 * ATTS];
    __shared__ bf16 Vs[64 * ATTS];
    __shared__ bf16 Ps[64 * ATTS];
    int tid = threadIdx.x, wave = tid >> 6, lane = tid & 63;
    int lr = lane & 15, quad = lane >> 4;

#pragma unroll
    for (int it = 0; it < 2; ++it) {
        int cidx = tid + it * 256;
        int row = cidx >> 3, ch = cidx & 7;
        *(bf16x8*)(Qs + row * ATTS + ch * 8) = *(const bf16x8*)(Qg + row * 64 + ch * 8);
    }
    float mrow[4], lrow[4];
    floatx4 Oacc[4];
#pragma unroll
    for (int r = 0; r < 4; ++r) { mrow[r] = -1e30f; lrow[r] = 0.f; }
#pragma unroll
    for (int d0 = 0; d0 < 4; ++d0) Oacc[d0] = (floatx4){0.f, 0.f, 0.f, 0.f};

    int ntiles = qt + 1;
    for (int t = 0; t < ntiles; ++t) {
        int kv0 = t * 64;
        __syncthreads();
#pragma unroll
        for (int it = 0; it < 2; ++it) {
            int cidx = tid + it * 256;
            int row = cidx >> 3, ch = cidx & 7;
            *(bf16x8*)(Ks + row * ATTS + ch * 8) =
                *(const bf16x8*)(Kg + (size_t)(kv0 + row) * 64 + ch * 8);
            *(bf16x8*)(Vs + row * ATTS + ch * 8) =
                *(const bf16x8*)(Vg + (size_t)row * 1024 + kv0 + ch * 8);
        }
        __syncthreads();
        bf16x8 aq[2];
#pragma unroll
        for (int kc = 0; kc < 2; ++kc)
            aq[kc] = *(const bf16x8*)(Qs + (wave * 16 + lr) * ATTS + kc * 32 + quad * 8);
        floatx4 sacc[4];
#pragma unroll
        for (int n0 = 0; n0 < 4; ++n0) {
            bf16x8 bk0 = *(const bf16x8*)(Ks + (n0 * 16 + lr) * ATTS + quad * 8);
            bf16x8 bk1 = *(const bf16x8*)(Ks + (n0 * 16 + lr) * ATTS + 32 + quad * 8);
            floatx4 z = (floatx4){0.f, 0.f, 0.f, 0.f};
            z = __builtin_amdgcn_mfma_f32_16x16x32_bf16(aq[0], bk0, z, 0, 0, 0);
            sacc[n0] = __builtin_amdgcn_mfma_f32_16x16x32_bf16(aq[1], bk1, z, 0, 0, 0);
        }
        float sv[4][4];
#pragma unroll
        for (int n0 = 0; n0 < 4; ++n0)
#pragma unroll
            for (int r = 0; r < 4; ++r) sv[n0][r] = sacc[n0][r] * 0.125f;
        if (t == ntiles - 1) {
#pragma unroll
            for (int n0 = 0; n0 < 4; ++n0)
#pragma unroll
                for (int r = 0; r < 4; ++r)
                    if (n0 * 16 + lr > wave * 16 + quad * 4 + r) sv[n0][r] = -1e30f;
        }
        float al[4];
#pragma unroll
        for (int r = 0; r < 4; ++r) {
            float tm = fmaxf(fmaxf(sv[0][r], sv[1][r]), fmaxf(sv[2][r], sv[3][r]));
            tm = fmaxf(tm, __shfl_xor(tm, 1));
            tm = fmaxf(tm, __shfl_xor(tm, 2));
            tm = fmaxf(tm, __shfl_xor(tm, 4));
            tm = fmaxf(tm, __shfl_xor(tm, 8));
            float mn = fmaxf(mrow[r], tm);
            al[r] = __expf(mrow[r] - mn);
            mrow[r] = mn;
        }
        float rs[4];
#pragma unroll
        for (int r = 0; r < 4; ++r) rs[r] = 0.f;
#pragma unroll
        for (int n0 = 0; n0 < 4; ++n0)
#pragma unroll
            for (int r = 0; r < 4; ++r) {
                float p = __expf(sv[n0][r] - mrow[r]);
                sv[n0][r] = p;
                rs[r] += p;
            }
#pragma unroll
        for (int r = 0; r < 4; ++r) {
            float t2 = rs[r];
            t2 += __shfl_xor(t2, 1);
            t2 += __shfl_xor(t2, 2);
            t2 += __shfl_xor(t2, 4);
            t2 += __shfl_xor(t2, 8);
            lrow[r] = lrow[r] * al[r] + t2;
        }
#pragma unroll
        for (int d0 = 0; d0 < 4; ++d0)
#pragma unroll
            for (int r = 0; r < 4; ++r) Oacc[d0][r] *= al[r];
#pragma unroll
        for (int n0 = 0; n0 < 4; ++n0)
#pragma unroll
            for (int r = 0; r < 4; ++r)
                Ps[(wave * 16 + quad * 4 + r) * ATTS + n0 * 16 + lr] = (bf16)sv[n0][r];
        bf16x8 ap[2];
#pragma unroll
        for (int kc = 0; kc < 2; ++kc)
            ap[kc] = *(const bf16x8*)(Ps + (wave * 16 + lr) * ATTS + kc * 32 + quad * 8);
#pragma unroll
        for (int d0 = 0; d0 < 4; ++d0) {
            bf16x8 bv0 = *(const bf16x8*)(Vs + (d0 * 16 + lr) * ATTS + quad * 8);
            bf16x8 bv1 = *(const bf16x8*)(Vs + (d0 * 16 + lr) * ATTS + 32 + quad * 8);
            Oacc[d0] = __builtin_amdgcn_mfma_f32_16x16x32_bf16(ap[0], bv0, Oacc[d0], 0, 0, 0);
            Oacc[d0] = __builtin_amdgcn_mfma_f32_16x16x32_bf16(ap[1], bv1, Oacc[d0], 0, 0, 0);
        }
    }
    float inv[4];
#pragma unroll
    for (int r = 0; r < 4; ++r) inv[r] = 1.f / lrow[r];
#pragma unroll
    for (int d0 = 0; d0 < 4; ++d0)
#pragma unroll
        for (int r = 0; r < 4; ++r) {
            int row = b * 1024 + q0 + wave * 16 + quad * 4 + r;
            int col = hh * 64 + d0 * 16 + lr;
            O[(size_t)row * 512 + col] = (bf16)(Oacc[d0][r] * inv[r]);
        }
}

// ------------------------------- delta scan --------------------------------
// 32 blocks (one per b,h) x 4 waves. Wave w owns S rows w*8..w*8+7; lane =
// (row, col group of 4). DPP sum8 reductions; LDS ctx staging; descaled
// state with branchless 16-step rescale. (verified round 7: 142 us)
__global__ __launch_bounds__(256, 1) void delta_scan(
    const float* __restrict__ P, const float* __restrict__ S_in,
    const float* __restrict__ bbias, const float* __restrict__ abias,
    float* __restrict__ S_out, float* __restrict__ ctx) {
    int bh = blockIdx.x;
    int b = bh >> 3, hh = bh & 7;
    int tid = threadIdx.x;
    int lane = tid & 63, wave = tid >> 6;
    int ri = wave * 8 + (lane >> 3);
    int c = lane & 7;
    bool cz = (c == 0);
    __shared__ __align__(16) float ks[66][36], qs[66][36], vs[66][36],
                                   bs[66][36], as_[66][36];
    __shared__ __align__(16) float cs[64][32];
    float4 S = *(const float4*)(S_in + ((size_t)bh * 32 + ri) * 32 + c * 4);

    int sc4 = tid & 7, sr0 = tid >> 3;   // staging: token rows sr0, sr0+32
    float4 bB = *(const float4*)(bbias + hh * 32 + sc4 * 4);
    float4 bA = *(const float4*)(abias + hh * 32 + sc4 * 4);
    float D = 1.f, Dinv = 1.f;

    float4 ka, qa, kb, qb;
    float aa, ba, va, a2, b2, v2;

    auto loadt = [&](int t, float4& k4, float4& q4, float& ax, float& bx, float& vx) {
        k4 = *(const float4*)&ks[t][c * 4];
        q4 = *(const float4*)&qs[t][c * 4];
        ax = as_[t][ri]; bx = bs[t][ri]; vx = vs[t][ri];
    };
    auto stepf = [&](float4 k4, float4 q4, float ax, float bx, float vx, int t) {
        float d = fmaf(S.w, k4.w, fmaf(S.z, k4.z, fmaf(S.y, k4.y, S.x * k4.x)));
        float dot = sum8(d);
        float u = bx * (vx - ax * (D * dot));
        D *= ax;
        Dinv *= __builtin_amdgcn_rcpf(ax);
        float ud = u * Dinv;
        S.x = fmaf(ud, k4.x, S.x);
        S.y = fmaf(ud, k4.y, S.y);
        S.z = fmaf(ud, k4.z, S.z);
        S.w = fmaf(ud, k4.w, S.w);
        float e = fmaf(S.w, q4.w, fmaf(S.z, q4.z, fmaf(S.y, q4.y, S.x * q4.x)));
        float rd = sum8(e);
        if (cz) cs[t][ri] = D * rd;
    };

    for (int c0 = 0; c0 < LSEQ; c0 += 64) {
        __syncthreads();
        const float* Pb = P + ((size_t)(b * 1024 + c0) * 1536) + hh * 32 + sc4 * 4;
#pragma unroll
        for (int it = 0; it < 2; ++it) {
            int tok = sr0 + it * 32;
            const float* pg = Pb + (size_t)tok * 1536;
            float4 kv = *(const float4*)(pg);
            float4 vv = *(const float4*)(pg + 256);
            float4 qv = *(const float4*)(pg + 512);
            float4 bv = *(const float4*)(pg + 768);
            float4 av = *(const float4*)(pg + 1024);
            float ss = kv.x * kv.x + kv.y * kv.y + kv.z * kv.z + kv.w * kv.w;
            ss = sum8(ss);
            float rn = 1.f / fmaxf(sqrtf(ss), 1e-12f);
            kv.x *= rn; kv.y *= rn; kv.z *= rn; kv.w *= rn;
            *(float4*)&ks[tok][sc4 * 4] = kv;
            *(float4*)&vs[tok][sc4 * 4] = vv;
            *(float4*)&qs[tok][sc4 * 4] = qv;
            float4 bo, ao;
            bo.x = 1.f / (1.f + __expf(-(bv.x + bB.x)));
            bo.y = 1.f / (1.f + __expf(-(bv.y + bB.y)));
            bo.z = 1.f / (1.f + __expf(-(bv.z + bB.z)));
            bo.w = 1.f / (1.f + __expf(-(bv.w + bB.w)));
            ao.x = 1.f / (1.f + __expf(-(av.x + bA.x)));
            ao.y = 1.f / (1.f + __expf(-(av.y + bA.y)));
            ao.z = 1.f / (1.f + __expf(-(av.z + bA.z)));
            ao.w = 1.f / (1.f + __expf(-(av.w + bA.w)));
            *(float4*)&bs[tok][sc4 * 4] = bo;
            *(float4*)&as_[tok][sc4 * 4] = ao;
        }
        __syncthreads();
#pragma unroll
        for (int sb = 0; sb < 4; ++sb) {
            int t0 = sb * 16;
            loadt(t0, ka, qa, aa, ba, va);
            for (int t = 0; t < 16; t += 2) {
                loadt(t0 + t + 1, kb, qb, a2, b2, v2);
                stepf(ka, qa, aa, ba, va, t0 + t);
                loadt(t0 + t + 2, ka, qa, aa, ba, va);   // t==64 pad row: unused
                stepf(kb, qb, a2, b2, v2, t0 + t + 1);
            }
            S.x *= D; S.y *= D; S.z *= D; S.w *= D;
            D = 1.f; Dinv = 1.f;
        }
        __syncthreads();
        int gbase = b * 1024 + c0;
        for (int e = tid; e < 512; e += 256) {
            int t = e >> 3, j4 = e & 7;
            float4 val = *(const float4*)&cs[t][j4 * 4];
            *(float4*)(ctx + (size_t)(gbase + t) * 256 + hh * 32 + j4 * 4) = val;
        }
    }
    *(float4*)(S_out + ((size_t)bh * 32 + ri) * 32 + c * 4) = S;
}

// ------------- ctxbf = bf16(rmsnorm(ctx,nw)*silu(gate)), gate in P@1280 ----
__global__ void ctx_post(const float* __restrict__ ctx, const float* __restrict__ P,
                         const float* __restrict__ nw, bf16* __restrict__ out) {
    int row = blockIdx.x, t = threadIdx.x;  // 64 threads
    float4 x = ((const float4*)(ctx + (size_t)row * SDIMM))[t];
    float s = x.x * x.x + x.y * x.y + x.z * x.z + x.w * x.w;
    for (int m = 1; m < 64; m <<= 1) s += __shfl_xor(s, m);
    float r = rsqrtf(s * (1.f / 256.f) + 1e-6f);
    float4 n = ((const float4*)nw)[t];
    float4 g = ((const float4*)(P + (size_t)row * 1536 + 1280))[t];
    BF4 u;
    u.h[0] = (bf16)(x.x * r * n.x * (g.x / (1.f + __expf(-g.x))));
    u.h[1] = (bf16)(x.y * r * n.y * (g.y / (1.f + __expf(-g.y))));
    u.h[2] = (bf16)(x.z * r * n.z * (g.z / (1.f + __expf(-g.z))));
    u.h[3] = (bf16)(x.w * r * n.w * (g.w / (1.f + __expf(-g.w))));
    ((short4*)(out + (size_t)row * SDIMM))[t] = u.p;
}

// ---------------------------------------------------------------------------
extern "C" void kernel_launch(void* const* d_in, const int* in_sizes, int n_in,
                              void* d_out, int out_size, void* d_ws, size_t ws_size,
                              hipStream_t stream) {
    (void)in_sizes; (void)n_in; (void)out_size; (void)ws_size;
    const int* ids = (const int*)d_in[0];
    const float* state = (const float*)d_in[1];
    const float* embedw = (const float*)d_in[2];
    auto F = [&](int i) { return (const float*)d_in[i]; };

    char* wsb = (char*)d_ws;
    const size_t MB = 1048576;
    float* H    = (float*)(wsb);                 // 0-8 MB
    bf16*  XNbf = (bf16*)(wsb + 8 * MB);         // 8-12 (alias ctxf in delta)
    float* ctxf = (float*)(wsb + 8 * MB);
    bf16*  Hbf  = (bf16*)(wsb + 12 * MB);        // 12-16 (alias ctxb)
    bf16*  ctxb = (bf16*)(wsb + 12 * MB);
    float* P    = (float*)(wsb + 16 * MB);       // 16-40 (delta proj f32)
    bf16*  Obf  = (bf16*)(wsb + 40 * MB);        // 40-44 attn out
    bf16*  Qbuf = (bf16*)(wsb + 44 * MB);        // 44-48
    bf16*  Kbuf = (bf16*)(wsb + 48 * MB);        // 48-52
    bf16*  Vtb  = (bf16*)(wsb + 52 * MB);        // 52-56
    bf16*  A1b  = (bf16*)(wsb + 44 * MB);        // alias Q/K/Vt (dead after attn)
    float* cosT = (float*)(wsb + 58 * MB);
    float* sinT = cosT + 32768;
    float* Sbuf = sinT + 32768;
    char*  wbase = wsb + 59 * MB;
    bf16* wqkv  = (bf16*)(wbase);                        // 6x1536x512
    bf16* wob   = (bf16*)(wbase + 9437184);              // 6x512x512
    bf16* wgu   = (bf16*)(wbase + 12582912);             // 6x3072x512 interleaved
    bf16* wdnb  = (bf16*)(wbase + 31457280);             // 6x512x1536
    bf16* wdR   = (bf16*)(wbase + 40894464);             // 1536x512
    bf16* woutR = (bf16*)(wbase + 42467328);             // 512x256
    bf16* wdW   = (bf16*)(wbase + 42729472);             // 1536x512
    bf16* woutW = (bf16*)(wbase + 44302336);             // 512x256
    bf16* embp  = (bf16*)(wbase + 44564480);             // 128x512 padded

    float* out = (float*)d_out;
    float* logits = out;
    float* Sout = out + 4096 * VOCN;

    // 128x128-tile launches
    auto G0 = [&](const bf16* A, const bf16* B, float* C, int M, int N, int K, int Nreal) {
        gemm_bf16<0><<<dim3(N / 128, M / 128), 256, 0, stream>>>(
            A, B, C, nullptr, nullptr, nullptr, nullptr, nullptr, nullptr, M, N, K, Nreal);
    };
    auto G4 = [&](const bf16* A, const bf16* B, bf16* Cb, int M, int N, int K, int Nreal) {
        gemm_bf16<4><<<dim3(N / 128, M / 128), 256, 0, stream>>>(
            A, B, nullptr, Cb, nullptr, nullptr, nullptr, nullptr, nullptr, M, N, K, Nreal);
    };
    auto G5 = [&](const bf16* A, const bf16* B, int M, int N, int K) {
        gemm_bf16<5><<<dim3(N / 128, M / 128), 256, 0, stream>>>(
            A, B, nullptr, nullptr, cosT, sinT, Qbuf, Kbuf, Vtb, M, N, K, N);
    };
    // 64x128-tile accumulate
    auto G1s = [&](const bf16* A, const bf16* B, float* C, int M, int N, int K) {
        gemm64_bf16<1><<<dim3(N / 128, M / 64), 256, 0, stream>>>(A, B, C, M, N, K, N);
    };
    auto G0s = [&](const bf16* A, const bf16* B, float* C, int M, int N, int K, int Nreal) {
        gemm64_bf16<0><<<dim3(N / 128, M / 64), 256, 0, stream>>>(A, B, C, M, N, K, Nreal);
    };
    auto CP = [&](const float* s, bf16* d, int n4) {
        cast_plain<<<(n4 + 255) / 256, 256, 0, stream>>>(s, d, n4);
    };

    // ---- weight casts ----
    cast_qkv<<<4608, 256, 0, stream>>>(F(24), F(25), F(26), wqkv);
    CP(F(27), wob, 393216);
    cast_gu<<<9216, 256, 0, stream>>>(F(29), F(30), wgu);
    CP(F(31), wdnb, 1179648);
    cast6<<<768, 256, 0, stream>>>(F(3), F(4), F(5), F(6), F(8), F(12), wdR);
    CP(F(10), woutR, 32768);
    cast6<<<768, 256, 0, stream>>>(F(13), F(14), F(15), F(16), F(18), F(22), wdW);
    CP(F(20), woutW, 32768);
    cast_embed_pad<<<64, 256, 0, stream>>>(embedw, embp);

    rope_tables_k<<<128, 256, 0, stream>>>(cosT, sinT);
    embed_k<<<4096, 128, 0, stream>>>(ids, embedw, H);

    // ---- delta read ----
    CP(H, Hbf, 524288);
    G0(Hbf, wdR, P, 4096, 1536, 512, 1536);
    delta_scan<<<32, 256, 0, stream>>>(P, state, F(7), F(9), Sbuf, ctxf);
    ctx_post<<<4096, 64, 0, stream>>>(ctxf, P, F(11), ctxb);
    G1s(ctxb, woutR, H, 4096, 512, 256);

    for (int i = 0; i < 6; ++i) {
        rmsnorm512<<<4096, 128, 0, stream>>>(H, F(23) + (size_t)i * 512, XNbf);
        G5(XNbf, wqkv + (size_t)i * 1536 * 512, 4096, 1536, 512);
        attn_mfma<<<dim3(16, 8, 4), 256, 0, stream>>>(Qbuf, Kbuf, Vtb, Obf);
        G1s(Obf, wob + (size_t)i * 512 * 512, H, 4096, 512, 512);
        rmsnorm512<<<4096, 128, 0, stream>>>(H, F(28) + (size_t)i * 512, XNbf);
        G4(XNbf, wgu + (size_t)i * 3072 * 512, A1b, 4096, 3072, 512, 1536);
        G1s(A1b, wdnb + (size_t)i * 512 * 1536, H, 4096, 512, 1536);
    }

    // ---- delta write ----
    CP(H, Hbf, 524288);
    G0(Hbf, wdW, P, 4096, 1536, 512, 1536);
    delta_scan<<<32, 256, 0, stream>>>(P, Sbuf, F(17), F(19), Sout, ctxf);
    ctx_post<<<4096, 64, 0, stream>>>(ctxf, P, F(21), ctxb);
    G1s(ctxb, woutW, H, 4096, 512, 256);

    rmsnorm512<<<4096, 128, 0, stream>>>(H, F(32), XNbf);
    G0s(XNbf, embp, logits, 4096, 128, 512, VOCN);
}